// Round 2
// baseline (2644.373 us; speedup 1.0000x reference)
//
#include <hip/hip_runtime.h>
#include <hip/hip_bf16.h>

typedef __hip_bfloat16 bf16;

#define N_NODES 100000
#define N_EDGES 1600000
#define D_IN    100
#define D_HID   50
#define N_REL   237
#define N_REL2  474
#define N_CLASS 50
#define YCOLS   300   // 5*50 basis cols + 50 root cols

// Canonical fp32 weight-block offsets (element offsets into wc)
#define O_RELEMB 0
#define O_RELW   23700
#define O_BASIS1 28700
#define O_COMP1  53700
#define O_ROOT1  56070
#define O_BIAS1  61070
#define O_BASIS2 61120
#define O_COMP2  73620
#define O_ROOT2  75990
#define O_BIAS2  78490
#define W_TOTAL  78540

__device__ __forceinline__ float b2f(bf16 v) { return __bfloat162float(v); }
__device__ __forceinline__ bf16  f2b(float v) { return __float2bfloat16(v); }

// ---- dtype detection: flag[0]=1 if float arrays are stored as bf16, 0 if fp32.
// Looks at even-indexed 16-bit halves of x. bf16 storage: exponent of N(0,1)
// values lands in [107,132] (~100%). fp32 storage: those halves are mantissa
// bits -> uniform exponent (~10% in range).
__global__ void k_detect(const unsigned short* __restrict__ xr, int* __restrict__ flag) {
    int tid = threadIdx.x;           // 256 threads, 1 block
    int cnt = 0;
    for (int i = tid; i < 4096; i += 256) {
        unsigned short u = xr[2 * i];
        unsigned e = (u >> 7) & 0xFF;
        bool pl = (e >= 107 && e <= 132) || ((u & 0x7FFF) == 0);
        cnt += pl ? 1 : 0;
    }
    __shared__ int sh[256];
    sh[tid] = cnt;
    __syncthreads();
    for (int s = 128; s > 0; s >>= 1) {
        if (tid < s) sh[tid] += sh[tid + s];
        __syncthreads();
    }
    if (tid == 0) flag[0] = (sh[0] >= 3072) ? 1 : 0;
}

// ---- canonicalize x -> bf16
__global__ void k_convert_x(const void* __restrict__ xr, const int* __restrict__ flag,
                            bf16* __restrict__ xc, int n) {
    int g = blockIdx.x * blockDim.x + threadIdx.x;
    if (g >= n) return;
    if (flag[0]) xc[g] = ((const bf16*)xr)[g];
    else         xc[g] = f2b(((const float*)xr)[g]);
}

struct WPtrs { const void* p[10]; };

// ---- canonicalize the 10 small float arrays -> one fp32 block wc
__global__ void k_convert_w(WPtrs wp, const int* __restrict__ flag, float* __restrict__ wc) {
    const int sz[10] = {23700, 5000, 25000, 2370, 5000, 50, 12500, 2370, 2500, 50};
    int g = blockIdx.x * blockDim.x + threadIdx.x;
    if (g >= W_TOTAL) return;
    int j = 0, base = 0;
    while (j < 9 && g >= base + sz[j]) { base += sz[j]; ++j; }
    int idx = g - base;
    float v;
    if (flag[0]) v = b2f(((const bf16*)wp.p[j])[idx]);
    else         v = ((const float*)wp.p[j])[idx];
    wc[g] = v;
}

// ---- pack basis [5][K][50] + root [K][50] (fp32) into W [K][300] (bf16)
__global__ void k_pack(const float* __restrict__ basis, const float* __restrict__ root,
                       bf16* __restrict__ Wp, int K) {
    int g = blockIdx.x * blockDim.x + threadIdx.x;
    int total = K * YCOLS;
    if (g >= total) return;
    int k = g / YCOLS, c = g - k * YCOLS;
    float v;
    if (c < 250) {
        int b = c / 50, f = c - b * 50;
        v = basis[(b * K + k) * 50 + f];
    } else {
        v = root[k * 50 + (c - 250)];
    }
    Wp[g] = f2b(v);
}

// ---- per-relation constant terms for both layers (all fp32 now)
__global__ void k_rel(const float* __restrict__ wc,
                      float* __restrict__ rt1, float* __restrict__ rt2) {
    const float* rel_emb = wc + O_RELEMB;
    const float* rel_w   = wc + O_RELW;
    const float* basis1  = wc + O_BASIS1;
    const float* comp1   = wc + O_COMP1;
    const float* basis2  = wc + O_BASIS2;
    const float* comp2   = wc + O_COMP2;
    int t = blockIdx.x;          // 474
    int tid = threadIdx.x;       // 64
    __shared__ float rf[D_IN];
    __shared__ float r2[D_HID];
    int tm = (t >= N_REL) ? t - N_REL : t;
    for (int k = tid; k < D_IN; k += 64) rf[k] = rel_emb[tm * D_IN + k];
    __syncthreads();
    if (tid < 50) {
        int f = tid;
        float a = 0.f;
        for (int b = 0; b < 5; ++b) {
            float cb = comp1[t * 5 + b];
            float s = 0.f;
            for (int k = 0; k < D_IN; ++k) s += rf[k] * basis1[(b * D_IN + k) * 50 + f];
            a += cb * s;
        }
        rt1[t * 50 + f] = a;
        float s2 = 0.f;
        for (int k = 0; k < D_IN; ++k) s2 += rf[k] * rel_w[k * 50 + f];
        r2[f] = s2;
    }
    __syncthreads();
    if (tid < 50) {
        int f = tid;
        float a = 0.f;
        for (int b = 0; b < 5; ++b) {
            float cb = comp2[t * 5 + b];
            float s = 0.f;
            for (int k = 0; k < 50; ++k) s += r2[k] * basis2[(b * 50 + k) * 50 + f];
            a += cb * s;
        }
        rt2[t * 50 + f] = a;
    }
}

// ---- Y[M,300] = X[M,K] @ W[K,300], W staged in LDS (bf16), fp32 accumulate.
template<int K>
__global__ __launch_bounds__(320) void k_gemm(const bf16* __restrict__ X,
                                              const bf16* __restrict__ Wp,
                                              bf16* __restrict__ Y, int M) {
    __shared__ bf16 Wl[K * YCOLS];
    {
        const uint32_t* s = (const uint32_t*)Wp;
        uint32_t* d = (uint32_t*)Wl;
        for (int i = threadIdx.x; i < K * YCOLS / 2; i += 320) d[i] = s[i];
    }
    __syncthreads();
    int c = threadIdx.x;
    int cc = (c < YCOLS) ? c : (YCOLS - 1);
    bool cok = (c < YCOLS);
    int r0 = blockIdx.x * 64;
    for (int r4 = 0; r4 < 64; r4 += 4) {
        int rr = r0 + r4;
        size_t x0 = (size_t)min(rr + 0, M - 1) * K;
        size_t x1 = (size_t)min(rr + 1, M - 1) * K;
        size_t x2 = (size_t)min(rr + 2, M - 1) * K;
        size_t x3 = (size_t)min(rr + 3, M - 1) * K;
        float a0 = 0.f, a1 = 0.f, a2 = 0.f, a3 = 0.f;
        for (int k = 0; k < K; ++k) {
            float w = b2f(Wl[k * YCOLS + cc]);
            a0 += w * b2f(X[x0 + k]);
            a1 += w * b2f(X[x1 + k]);
            a2 += w * b2f(X[x2 + k]);
            a3 += w * b2f(X[x3 + k]);
        }
        if (cok) {
            if (rr + 0 < M) Y[(size_t)(rr + 0) * YCOLS + c] = f2b(a0);
            if (rr + 1 < M) Y[(size_t)(rr + 1) * YCOLS + c] = f2b(a1);
            if (rr + 2 < M) Y[(size_t)(rr + 2) * YCOLS + c] = f2b(a2);
            if (rr + 3 < M) Y[(size_t)(rr + 3) * YCOLS + c] = f2b(a3);
        }
    }
}

// ---- zero Y row of target node (x[target]=0; Y is linear in x)
__global__ void k_zerorow(bf16* __restrict__ Y, const int* __restrict__ tgt) {
    int t = tgt[0];
    int i = threadIdx.x;
    if (i < YCOLS) Y[(size_t)t * YCOLS + i] = f2b(0.f);
}

// ---- per-edge combine + atomic scatter (thread = edge x 2 cols)
__global__ void k_edge(const int* __restrict__ src, const int* __restrict__ dst,
                       const int* __restrict__ et, const float* __restrict__ comp,
                       const float* __restrict__ relterm, const bf16* __restrict__ Y,
                       float* __restrict__ agg, float* __restrict__ cnt, int E) {
    unsigned g = blockIdx.x * blockDim.x + threadIdx.x;
    unsigned e = g / 25u;
    if (e >= (unsigned)E) return;
    int r  = (int)(g - e * 25u);
    int f0 = r * 2;
    int t = et[e];
    int s = src[e];
    int d = dst[e];
    const uint32_t* yrow = (const uint32_t*)(Y + (size_t)s * YCOLS);
    float2 rt = *(const float2*)(relterm + t * 50 + f0);
    float a0 = rt.x, a1 = rt.y;
#pragma unroll
    for (int b = 0; b < 5; ++b) {
        float cb = comp[t * 5 + b];
        uint32_t u = yrow[(b * 50 + f0) >> 1];
        float lo = __uint_as_float(u << 16);
        float hi = __uint_as_float(u & 0xffff0000u);
        a0 += cb * lo;
        a1 += cb * hi;
    }
    atomicAdd(agg + (size_t)d * 50 + f0,     a0);
    atomicAdd(agg + (size_t)d * 50 + f0 + 1, a1);
    if (cnt != nullptr && r == 0) atomicAdd(cnt + d, 1.0f);
}

// ---- layer-1 epilogue: h = agg/max(cnt,1) + x@root (Y cols 250..) + bias
__global__ void k_h(const float* __restrict__ agg, const float* __restrict__ cnt,
                    const bf16* __restrict__ Y, const float* __restrict__ bias,
                    bf16* __restrict__ h) {
    int g = blockIdx.x * blockDim.x + threadIdx.x;
    if (g >= N_NODES * 50) return;
    int n = g / 50, f = g - n * 50;
    float c = cnt[n]; c = c > 1.f ? c : 1.f;
    float v = agg[g] / c + b2f(Y[(size_t)n * YCOLS + 250 + f]) + bias[f];
    h[g] = f2b(v);
}

// ---- layer-2 epilogue + row log_softmax; dual-dtype output store
__global__ __launch_bounds__(256) void k_out(const float* __restrict__ agg,
                                             const float* __restrict__ cnt,
                                             const bf16* __restrict__ Y,
                                             const float* __restrict__ bias,
                                             const int* __restrict__ flag,
                                             void* __restrict__ out) {
    int wid  = threadIdx.x >> 6;
    int lane = threadIdx.x & 63;
    int row  = blockIdx.x * 4 + wid;
    if (row >= N_NODES) return;
    float c = cnt[row]; c = c > 1.f ? c : 1.f;
    float v = -INFINITY;
    if (lane < 50)
        v = agg[row * 50 + lane] / c + b2f(Y[(size_t)row * YCOLS + 250 + lane]) + bias[lane];
    float m = v;
    for (int off = 32; off > 0; off >>= 1) m = fmaxf(m, __shfl_xor(m, off));
    float ex = (lane < 50) ? expf(v - m) : 0.f;
    float s = ex;
    for (int off = 32; off > 0; off >>= 1) s += __shfl_xor(s, off);
    float res = v - m - logf(s);
    if (lane < 50) {
        if (flag[0]) ((bf16*)out)[row * 50 + lane] = f2b(res);
        else         ((float*)out)[row * 50 + lane] = res;
    }
}

extern "C" void kernel_launch(void* const* d_in, const int* in_sizes, int n_in,
                              void* d_out, int out_size, void* d_ws, size_t ws_size,
                              hipStream_t stream) {
    const void* x_raw = d_in[0];
    const int*  ei    = (const int*)d_in[1];
    const int*  et    = (const int*)d_in[2];
    const int*  tgt   = (const int*)d_in[3];

    char* wsp = (char*)d_ws;
    size_t off = 0;
    auto alloc = [&](size_t bytes) {
        void* p = wsp + off;
        off = (off + bytes + 255) & ~(size_t)255;
        return p;
    };
    bf16*  Y    = (bf16*) alloc((size_t)N_NODES * YCOLS * sizeof(bf16));   // 60 MB
    float* agg  = (float*)alloc((size_t)N_NODES * 50 * sizeof(float));     // 20 MB
    bf16*  xc   = (bf16*) alloc((size_t)N_NODES * D_IN * sizeof(bf16));    // 20 MB
    bf16*  h    = (bf16*) alloc((size_t)N_NODES * 50 * sizeof(bf16));      // 10 MB
    float* cnt  = (float*)alloc((size_t)N_NODES * sizeof(float));          // 0.4 MB
    float* wc   = (float*)alloc((size_t)W_TOTAL * sizeof(float));
    bf16*  W1p  = (bf16*) alloc((size_t)D_IN  * YCOLS * sizeof(bf16));
    bf16*  W2p  = (bf16*) alloc((size_t)D_HID * YCOLS * sizeof(bf16));
    float* rt1  = (float*)alloc((size_t)N_REL2 * 50 * sizeof(float));
    float* rt2  = (float*)alloc((size_t)N_REL2 * 50 * sizeof(float));
    int*   flag = (int*)  alloc(sizeof(int));

    const int* srcp = ei;
    const int* dstp = ei + N_EDGES;

    hipMemsetAsync(agg, 0, (size_t)N_NODES * 50 * sizeof(float), stream);
    hipMemsetAsync(cnt, 0, (size_t)N_NODES * sizeof(float), stream);

    // dtype detect + canonicalize
    k_detect<<<1, 256, 0, stream>>>((const unsigned short*)x_raw, flag);
    k_convert_x<<<(N_NODES * D_IN + 255) / 256, 256, 0, stream>>>(x_raw, flag, xc, N_NODES * D_IN);
    WPtrs wp;
    for (int i = 0; i < 10; ++i) wp.p[i] = d_in[4 + i];
    k_convert_w<<<(W_TOTAL + 255) / 256, 256, 0, stream>>>(wp, flag, wc);

    k_pack<<<(D_IN  * YCOLS + 255) / 256, 256, 0, stream>>>(wc + O_BASIS1, wc + O_ROOT1, W1p, D_IN);
    k_pack<<<(D_HID * YCOLS + 255) / 256, 256, 0, stream>>>(wc + O_BASIS2, wc + O_ROOT2, W2p, D_HID);
    k_rel<<<N_REL2, 64, 0, stream>>>(wc, rt1, rt2);

    // Layer 1
    k_gemm<D_IN><<<(N_NODES + 63) / 64, 320, 0, stream>>>(xc, W1p, Y, N_NODES);
    k_zerorow<<<1, 320, 0, stream>>>(Y, tgt);
    k_edge<<<(N_EDGES * 25) / 256, 256, 0, stream>>>(srcp, dstp, et, wc + O_COMP1, rt1, Y, agg, cnt, N_EDGES);
    k_h<<<(N_NODES * 50 + 255) / 256, 256, 0, stream>>>(agg, cnt, Y, wc + O_BIAS1, h);

    // Layer 2
    hipMemsetAsync(agg, 0, (size_t)N_NODES * 50 * sizeof(float), stream);
    k_gemm<D_HID><<<(N_NODES + 63) / 64, 320, 0, stream>>>(h, W2p, Y, N_NODES);
    k_edge<<<(N_EDGES * 25) / 256, 256, 0, stream>>>(srcp, dstp, et, wc + O_COMP2, rt2, Y, agg, nullptr, N_EDGES);
    k_out<<<(N_NODES + 3) / 4, 256, 0, stream>>>(agg, cnt, Y, wc + O_BIAS2, flag, d_out);
}

// Round 3
// 1656.976 us; speedup vs baseline: 1.5959x; 1.5959x over previous
//
#include <hip/hip_runtime.h>
#include <hip/hip_bf16.h>

typedef __hip_bfloat16 bf16;

#define N_NODES 100000
#define N_EDGES 1600000
#define D_IN    100
#define D_HID   50
#define N_REL   237
#define N_REL2  474
#define N_CLASS 50
#define YCOLS   300   // 5*50 basis cols + 50 root cols
#define NBLK    391   // ceil(N_NODES/256)

// Canonical fp32 weight-block offsets (element offsets into wc)
#define O_RELEMB 0
#define O_RELW   23700
#define O_BASIS1 28700
#define O_COMP1  53700
#define O_ROOT1  56070
#define O_BIAS1  61070
#define O_BASIS2 61120
#define O_COMP2  73620
#define O_ROOT2  75990
#define O_BIAS2  78490
#define W_TOTAL  78540

__device__ __forceinline__ float b2f(bf16 v) { return __bfloat162float(v); }
__device__ __forceinline__ bf16  f2b(float v) { return __float2bfloat16(v); }

// ---- dtype detection: flag[0]=1 if float arrays are stored as bf16, 0 if fp32.
__global__ void k_detect(const unsigned short* __restrict__ xr, int* __restrict__ flag) {
    int tid = threadIdx.x;           // 256 threads, 1 block
    int cnt = 0;
    for (int i = tid; i < 4096; i += 256) {
        unsigned short u = xr[2 * i];
        unsigned e = (u >> 7) & 0xFF;
        bool pl = (e >= 107 && e <= 132) || ((u & 0x7FFF) == 0);
        cnt += pl ? 1 : 0;
    }
    __shared__ int sh[256];
    sh[tid] = cnt;
    __syncthreads();
    for (int s = 128; s > 0; s >>= 1) {
        if (tid < s) sh[tid] += sh[tid + s];
        __syncthreads();
    }
    if (tid == 0) flag[0] = (sh[0] >= 3072) ? 1 : 0;
}

// ---- canonicalize x -> bf16
__global__ void k_convert_x(const void* __restrict__ xr, const int* __restrict__ flag,
                            bf16* __restrict__ xc, int n) {
    int g = blockIdx.x * blockDim.x + threadIdx.x;
    if (g >= n) return;
    if (flag[0]) xc[g] = ((const bf16*)xr)[g];
    else         xc[g] = f2b(((const float*)xr)[g]);
}

struct WPtrs { const void* p[10]; };

// ---- canonicalize the 10 small float arrays -> one fp32 block wc
__global__ void k_convert_w(WPtrs wp, const int* __restrict__ flag, float* __restrict__ wc) {
    const int sz[10] = {23700, 5000, 25000, 2370, 5000, 50, 12500, 2370, 2500, 50};
    int g = blockIdx.x * blockDim.x + threadIdx.x;
    if (g >= W_TOTAL) return;
    int j = 0, base = 0;
    while (j < 9 && g >= base + sz[j]) { base += sz[j]; ++j; }
    int idx = g - base;
    float v;
    if (flag[0]) v = b2f(((const bf16*)wp.p[j])[idx]);
    else         v = ((const float*)wp.p[j])[idx];
    wc[g] = v;
}

// ---- pack basis [5][K][50] + root [K][50] (fp32) into W [K][300] (bf16)
__global__ void k_pack(const float* __restrict__ basis, const float* __restrict__ root,
                       bf16* __restrict__ Wp, int K) {
    int g = blockIdx.x * blockDim.x + threadIdx.x;
    int total = K * YCOLS;
    if (g >= total) return;
    int k = g / YCOLS, c = g - k * YCOLS;
    float v;
    if (c < 250) {
        int b = c / 50, f = c - b * 50;
        v = basis[(b * K + k) * 50 + f];
    } else {
        v = root[k * 50 + (c - 250)];
    }
    Wp[g] = f2b(v);
}

// ---- per-relation constant terms for both layers
__global__ void k_rel(const float* __restrict__ wc,
                      float* __restrict__ rt1, float* __restrict__ rt2) {
    const float* rel_emb = wc + O_RELEMB;
    const float* rel_w   = wc + O_RELW;
    const float* basis1  = wc + O_BASIS1;
    const float* comp1   = wc + O_COMP1;
    const float* basis2  = wc + O_BASIS2;
    const float* comp2   = wc + O_COMP2;
    int t = blockIdx.x;          // 474
    int tid = threadIdx.x;       // 64
    __shared__ float rf[D_IN];
    __shared__ float r2[D_HID];
    int tm = (t >= N_REL) ? t - N_REL : t;
    for (int k = tid; k < D_IN; k += 64) rf[k] = rel_emb[tm * D_IN + k];
    __syncthreads();
    if (tid < 50) {
        int f = tid;
        float a = 0.f;
        for (int b = 0; b < 5; ++b) {
            float cb = comp1[t * 5 + b];
            float s = 0.f;
            for (int k = 0; k < D_IN; ++k) s += rf[k] * basis1[(b * D_IN + k) * 50 + f];
            a += cb * s;
        }
        rt1[t * 50 + f] = a;
        float s2 = 0.f;
        for (int k = 0; k < D_IN; ++k) s2 += rf[k] * rel_w[k * 50 + f];
        r2[f] = s2;
    }
    __syncthreads();
    if (tid < 50) {
        int f = tid;
        float a = 0.f;
        for (int b = 0; b < 5; ++b) {
            float cb = comp2[t * 5 + b];
            float s = 0.f;
            for (int k = 0; k < 50; ++k) s += r2[k] * basis2[(b * 50 + k) * 50 + f];
            a += cb * s;
        }
        rt2[t * 50 + f] = a;
    }
}

// ---- Y[M,300] = X[M,K] @ W[K,300], W staged in LDS (bf16), fp32 accumulate.
template<int K>
__global__ __launch_bounds__(320) void k_gemm(const bf16* __restrict__ X,
                                              const bf16* __restrict__ Wp,
                                              bf16* __restrict__ Y, int M) {
    __shared__ bf16 Wl[K * YCOLS];
    {
        const uint32_t* s = (const uint32_t*)Wp;
        uint32_t* d = (uint32_t*)Wl;
        for (int i = threadIdx.x; i < K * YCOLS / 2; i += 320) d[i] = s[i];
    }
    __syncthreads();
    int c = threadIdx.x;
    int cc = (c < YCOLS) ? c : (YCOLS - 1);
    bool cok = (c < YCOLS);
    int r0 = blockIdx.x * 64;
    for (int r4 = 0; r4 < 64; r4 += 4) {
        int rr = r0 + r4;
        size_t x0 = (size_t)min(rr + 0, M - 1) * K;
        size_t x1 = (size_t)min(rr + 1, M - 1) * K;
        size_t x2 = (size_t)min(rr + 2, M - 1) * K;
        size_t x3 = (size_t)min(rr + 3, M - 1) * K;
        float a0 = 0.f, a1 = 0.f, a2 = 0.f, a3 = 0.f;
        for (int k = 0; k < K; ++k) {
            float w = b2f(Wl[k * YCOLS + cc]);
            a0 += w * b2f(X[x0 + k]);
            a1 += w * b2f(X[x1 + k]);
            a2 += w * b2f(X[x2 + k]);
            a3 += w * b2f(X[x3 + k]);
        }
        if (cok) {
            if (rr + 0 < M) Y[(size_t)(rr + 0) * YCOLS + c] = f2b(a0);
            if (rr + 1 < M) Y[(size_t)(rr + 1) * YCOLS + c] = f2b(a1);
            if (rr + 2 < M) Y[(size_t)(rr + 2) * YCOLS + c] = f2b(a2);
            if (rr + 3 < M) Y[(size_t)(rr + 3) * YCOLS + c] = f2b(a3);
        }
    }
}

// ---- zero Y row of target node (x[target]=0; Y is linear in x)
__global__ void k_zerorow(bf16* __restrict__ Y, const int* __restrict__ tgt) {
    int t = tgt[0];
    int i = threadIdx.x;
    if (i < YCOLS) Y[(size_t)t * YCOLS + i] = f2b(0.f);
}

// ================= CSR build (once; graph identical in both layers) ==========
__global__ void k_hist(const int* __restrict__ dst, int* __restrict__ cntI, int E) {
    int e = blockIdx.x * blockDim.x + threadIdx.x;
    if (e < E) atomicAdd(&cntI[dst[e]], 1);
}

__global__ void k_s1(const int* __restrict__ cntI, int* __restrict__ bsum) {
    __shared__ int sh[256];
    int i = blockIdx.x * 256 + threadIdx.x;
    sh[threadIdx.x] = (i < N_NODES) ? cntI[i] : 0;
    __syncthreads();
    for (int s = 128; s > 0; s >>= 1) {
        if (threadIdx.x < s) sh[threadIdx.x] += sh[threadIdx.x + s];
        __syncthreads();
    }
    if (threadIdx.x == 0) bsum[blockIdx.x] = sh[0];
}

__global__ void k_s2(int* __restrict__ bsum) {   // in-place exclusive scan, tiny
    if (threadIdx.x == 0) {
        int acc = 0;
        for (int i = 0; i < NBLK; ++i) { int t = bsum[i]; bsum[i] = acc; acc += t; }
    }
}

__global__ void k_s3(const int* __restrict__ cntI, const int* __restrict__ bsum,
                     int* __restrict__ off) {
    __shared__ int sh[256];
    int i = blockIdx.x * 256 + threadIdx.x;
    int v = (i < N_NODES) ? cntI[i] : 0;
    sh[threadIdx.x] = v;
    __syncthreads();
    for (int s = 1; s < 256; s <<= 1) {        // Hillis-Steele inclusive
        int t = (threadIdx.x >= (unsigned)s) ? sh[threadIdx.x - s] : 0;
        __syncthreads();
        sh[threadIdx.x] += t;
        __syncthreads();
    }
    int excl = sh[threadIdx.x] - v + bsum[blockIdx.x];
    if (i < N_NODES) off[i] = excl;
    if (i == N_NODES - 1) off[N_NODES] = excl + v;   // == N_EDGES
}

__global__ void k_scatter(const int* __restrict__ src, const int* __restrict__ dst,
                          const int* __restrict__ et, const int* __restrict__ off,
                          int* __restrict__ fill, unsigned int* __restrict__ se, int E) {
    int e = blockIdx.x * blockDim.x + threadIdx.x;
    if (e >= E) return;
    int d = dst[e];
    int pos = off[d] + atomicAdd(&fill[d], 1);
    se[pos] = (unsigned int)src[e] | ((unsigned int)et[e] << 17);   // src<2^17, et<2^9
}

// ================= per-node gather-reduce (no atomics) =======================
// Layer 1: h = mean_agg + x@root (Y cols 250..) + bias, bf16 out. 1 wave/node.
__global__ __launch_bounds__(256) void k_reduce1(const int* __restrict__ off,
                                                 const unsigned int* __restrict__ se,
                                                 const float* __restrict__ comp,
                                                 const float* __restrict__ rt,
                                                 const bf16* __restrict__ Y,
                                                 const float* __restrict__ bias_,
                                                 bf16* __restrict__ h) {
    int wid = threadIdx.x >> 6, lane = threadIdx.x & 63;
    int row = blockIdx.x * 4 + wid;
    if (row >= N_NODES) return;
    int e0 = off[row], e1 = off[row + 1];
    int f = (lane < 50) ? lane : 49;
    float acc = 0.f;
    for (int e = e0; e < e1; ++e) {
        unsigned int p = se[e];
        int s = (int)(p & 0x1FFFFu);
        int t = (int)(p >> 17);
        float a = rt[t * 50 + f];
        const bf16* yr = Y + (size_t)s * YCOLS;
#pragma unroll
        for (int b = 0; b < 5; ++b) a += comp[t * 5 + b] * b2f(yr[b * 50 + f]);
        acc += a;
    }
    float c = (float)(e1 - e0); c = c > 1.f ? c : 1.f;
    float v = acc / c + b2f(Y[(size_t)row * YCOLS + 250 + f]) + bias_[f];
    if (lane < 50) h[row * 50 + f] = f2b(v);
}

// Layer 2: same reduce + log_softmax epilogue; dual-dtype output store.
__global__ __launch_bounds__(256) void k_reduce2(const int* __restrict__ off,
                                                 const unsigned int* __restrict__ se,
                                                 const float* __restrict__ comp,
                                                 const float* __restrict__ rt,
                                                 const bf16* __restrict__ Y,
                                                 const float* __restrict__ bias_,
                                                 const int* __restrict__ flag,
                                                 void* __restrict__ out) {
    int wid = threadIdx.x >> 6, lane = threadIdx.x & 63;
    int row = blockIdx.x * 4 + wid;
    if (row >= N_NODES) return;
    int e0 = off[row], e1 = off[row + 1];
    int f = (lane < 50) ? lane : 49;
    float acc = 0.f;
    for (int e = e0; e < e1; ++e) {
        unsigned int p = se[e];
        int s = (int)(p & 0x1FFFFu);
        int t = (int)(p >> 17);
        float a = rt[t * 50 + f];
        const bf16* yr = Y + (size_t)s * YCOLS;
#pragma unroll
        for (int b = 0; b < 5; ++b) a += comp[t * 5 + b] * b2f(yr[b * 50 + f]);
        acc += a;
    }
    float c = (float)(e1 - e0); c = c > 1.f ? c : 1.f;
    float v = -INFINITY;
    if (lane < 50)
        v = acc / c + b2f(Y[(size_t)row * YCOLS + 250 + f]) + bias_[f];
    float m = v;
    for (int o = 32; o > 0; o >>= 1) m = fmaxf(m, __shfl_xor(m, o));
    float ex = (lane < 50) ? expf(v - m) : 0.f;
    float s = ex;
    for (int o = 32; o > 0; o >>= 1) s += __shfl_xor(s, o);
    float res = v - m - logf(s);
    if (lane < 50) {
        if (flag[0]) ((bf16*)out)[row * 50 + f] = f2b(res);
        else         ((float*)out)[row * 50 + f] = res;
    }
}

extern "C" void kernel_launch(void* const* d_in, const int* in_sizes, int n_in,
                              void* d_out, int out_size, void* d_ws, size_t ws_size,
                              hipStream_t stream) {
    const void* x_raw = d_in[0];
    const int*  ei    = (const int*)d_in[1];
    const int*  et    = (const int*)d_in[2];
    const int*  tgt   = (const int*)d_in[3];

    char* wsp = (char*)d_ws;
    size_t off_b = 0;
    auto alloc = [&](size_t bytes) {
        void* p = wsp + off_b;
        off_b = (off_b + bytes + 255) & ~(size_t)255;
        return p;
    };
    bf16*  Y    = (bf16*) alloc((size_t)N_NODES * YCOLS * sizeof(bf16));     // 60 MB
    bf16*  xc   = (bf16*) alloc((size_t)N_NODES * D_IN * sizeof(bf16));      // 20 MB
    bf16*  h    = (bf16*) alloc((size_t)N_NODES * 50 * sizeof(bf16));        // 10 MB
    unsigned int* se = (unsigned int*)alloc((size_t)N_EDGES * sizeof(unsigned int)); // 6.4 MB
    int*   cntI = (int*)  alloc((size_t)N_NODES * sizeof(int));
    int*   offs = (int*)  alloc((size_t)(N_NODES + 1) * sizeof(int));
    int*   fill = (int*)  alloc((size_t)N_NODES * sizeof(int));
    int*   bsum = (int*)  alloc((size_t)NBLK * sizeof(int));
    float* wc   = (float*)alloc((size_t)W_TOTAL * sizeof(float));
    bf16*  W1p  = (bf16*) alloc((size_t)D_IN  * YCOLS * sizeof(bf16));
    bf16*  W2p  = (bf16*) alloc((size_t)D_HID * YCOLS * sizeof(bf16));
    float* rt1  = (float*)alloc((size_t)N_REL2 * 50 * sizeof(float));
    float* rt2  = (float*)alloc((size_t)N_REL2 * 50 * sizeof(float));
    int*   flag = (int*)  alloc(sizeof(int));

    const int* srcp = ei;
    const int* dstp = ei + N_EDGES;

    hipMemsetAsync(cntI, 0, (size_t)N_NODES * sizeof(int), stream);
    hipMemsetAsync(fill, 0, (size_t)N_NODES * sizeof(int), stream);

    // dtype detect + canonicalize
    k_detect<<<1, 256, 0, stream>>>((const unsigned short*)x_raw, flag);
    k_convert_x<<<(N_NODES * D_IN + 255) / 256, 256, 0, stream>>>(x_raw, flag, xc, N_NODES * D_IN);
    WPtrs wp;
    for (int i = 0; i < 10; ++i) wp.p[i] = d_in[4 + i];
    k_convert_w<<<(W_TOTAL + 255) / 256, 256, 0, stream>>>(wp, flag, wc);

    k_pack<<<(D_IN  * YCOLS + 255) / 256, 256, 0, stream>>>(wc + O_BASIS1, wc + O_ROOT1, W1p, D_IN);
    k_pack<<<(D_HID * YCOLS + 255) / 256, 256, 0, stream>>>(wc + O_BASIS2, wc + O_ROOT2, W2p, D_HID);
    k_rel<<<N_REL2, 64, 0, stream>>>(wc, rt1, rt2);

    // CSR build (graph shared by both layers)
    k_hist<<<(N_EDGES + 255) / 256, 256, 0, stream>>>(dstp, cntI, N_EDGES);
    k_s1<<<NBLK, 256, 0, stream>>>(cntI, bsum);
    k_s2<<<1, 64, 0, stream>>>(bsum);
    k_s3<<<NBLK, 256, 0, stream>>>(cntI, bsum, offs);
    k_scatter<<<(N_EDGES + 255) / 256, 256, 0, stream>>>(srcp, dstp, et, offs, fill, se, N_EDGES);

    // Layer 1
    k_gemm<D_IN><<<(N_NODES + 63) / 64, 320, 0, stream>>>(xc, W1p, Y, N_NODES);
    k_zerorow<<<1, 320, 0, stream>>>(Y, tgt);
    k_reduce1<<<(N_NODES + 3) / 4, 256, 0, stream>>>(offs, se, wc + O_COMP1, rt1, Y, wc + O_BIAS1, h);

    // Layer 2
    k_gemm<D_HID><<<(N_NODES + 63) / 64, 320, 0, stream>>>(h, W2p, Y, N_NODES);
    k_reduce2<<<(N_NODES + 3) / 4, 256, 0, stream>>>(offs, se, wc + O_COMP2, rt2, Y, wc + O_BIAS2, flag, d_out);
}

// Round 4
// 665.325 us; speedup vs baseline: 3.9746x; 2.4905x over previous
//
#include <hip/hip_runtime.h>
#include <hip/hip_bf16.h>

typedef __hip_bfloat16 bf16;

#define N_NODES 100000
#define N_EDGES 1600000
#define D_IN    100
#define D_HID   50
#define N_REL   237
#define N_REL2  474
#define N_CLASS 50
#define YROW    320   // padded Y row stride: 250 basis + 50 root + 20 pad
#define NBLK    391   // ceil(N_NODES/256)

// Canonical fp32 weight-block offsets (element offsets into wc)
#define O_RELEMB 0
#define O_RELW   23700
#define O_BASIS1 28700
#define O_COMP1  53700
#define O_ROOT1  56070
#define O_BIAS1  61070
#define O_BASIS2 61120
#define O_COMP2  73620
#define O_ROOT2  75990
#define O_BIAS2  78490
#define W_TOTAL  78540

typedef __attribute__((ext_vector_type(8))) short short8;
typedef __attribute__((ext_vector_type(4))) float f32x4;

__device__ __forceinline__ float b2f(bf16 v) { return __bfloat162float(v); }
__device__ __forceinline__ bf16  f2b(float v) { return __float2bfloat16(v); }

// ---- dtype detection: flag[0]=1 if float arrays are stored as bf16, 0 if fp32.
__global__ void k_detect(const unsigned short* __restrict__ xr, int* __restrict__ flag) {
    int tid = threadIdx.x;
    int cnt = 0;
    for (int i = tid; i < 4096; i += 256) {
        unsigned short u = xr[2 * i];
        unsigned e = (u >> 7) & 0xFF;
        bool pl = (e >= 107 && e <= 132) || ((u & 0x7FFF) == 0);
        cnt += pl ? 1 : 0;
    }
    __shared__ int sh[256];
    sh[tid] = cnt;
    __syncthreads();
    for (int s = 128; s > 0; s >>= 1) {
        if (tid < s) sh[tid] += sh[tid + s];
        __syncthreads();
    }
    if (tid == 0) flag[0] = (sh[0] >= 3072) ? 1 : 0;
}

// ---- canonicalize x -> bf16, zero-padded to 128 cols
__global__ void k_convert_x(const void* __restrict__ xr, const int* __restrict__ flag,
                            bf16* __restrict__ xc) {
    int g = blockIdx.x * blockDim.x + threadIdx.x;
    if (g >= N_NODES * 128) return;
    int row = g >> 7, col = g & 127;
    bf16 o = f2b(0.f);
    if (col < D_IN) {
        if (flag[0]) o = ((const bf16*)xr)[row * D_IN + col];
        else         o = f2b(((const float*)xr)[row * D_IN + col]);
    }
    xc[g] = o;
}

struct WPtrs { const void* p[10]; };

// ---- canonicalize the 10 small float arrays -> one fp32 block wc
__global__ void k_convert_w(WPtrs wp, const int* __restrict__ flag, float* __restrict__ wc) {
    const int sz[10] = {23700, 5000, 25000, 2370, 5000, 50, 12500, 2370, 2500, 50};
    int g = blockIdx.x * blockDim.x + threadIdx.x;
    if (g >= W_TOTAL) return;
    int j = 0, base = 0;
    while (j < 9 && g >= base + sz[j]) { base += sz[j]; ++j; }
    int idx = g - base;
    float v;
    if (flag[0]) v = b2f(((const bf16*)wp.p[j])[idx]);
    else         v = ((const float*)wp.p[j])[idx];
    wc[g] = v;
}

// ---- pack basis[5][KL][50] + root[KL][50] into MFMA B-fragment order:
// Wb[((ks*20+ct)*64+lane)*8+j] = W[k=ks*32+(lane>>4)*8+j][n=ct*16+(lane&15)], zero-padded.
__global__ void k_pack_mfma(const float* __restrict__ basis, const float* __restrict__ root,
                            bf16* __restrict__ Wb, int KL, int KP) {
    int g = blockIdx.x * blockDim.x + threadIdx.x;
    int total = (KP >> 5) * 10240;
    if (g >= total) return;
    int ks = g / 10240;
    int r = g - ks * 10240;
    int ct = r >> 9;
    int r2 = r & 511;
    int l = r2 >> 3, j = r2 & 7;
    int k = ks * 32 + ((l >> 4) << 3) + j;
    int n = ct * 16 + (l & 15);
    float v = 0.f;
    if (k < KL && n < 300) {
        if (n < 250) { int b = n / 50, f = n - b * 50; v = basis[(b * KL + k) * 50 + f]; }
        else         v = root[k * 50 + (n - 250)];
    }
    Wb[g] = f2b(v);
}

// ---- per-relation constant terms for both layers
__global__ void k_rel(const float* __restrict__ wc,
                      float* __restrict__ rt1, float* __restrict__ rt2) {
    const float* rel_emb = wc + O_RELEMB;
    const float* rel_w   = wc + O_RELW;
    const float* basis1  = wc + O_BASIS1;
    const float* comp1   = wc + O_COMP1;
    const float* basis2  = wc + O_BASIS2;
    const float* comp2   = wc + O_COMP2;
    int t = blockIdx.x;
    int tid = threadIdx.x;
    __shared__ float rf[D_IN];
    __shared__ float r2[D_HID];
    int tm = (t >= N_REL) ? t - N_REL : t;
    for (int k = tid; k < D_IN; k += 64) rf[k] = rel_emb[tm * D_IN + k];
    __syncthreads();
    if (tid < 50) {
        int f = tid;
        float a = 0.f;
        for (int b = 0; b < 5; ++b) {
            float cb = comp1[t * 5 + b];
            float s = 0.f;
            for (int k = 0; k < D_IN; ++k) s += rf[k] * basis1[(b * D_IN + k) * 50 + f];
            a += cb * s;
        }
        rt1[t * 50 + f] = a;
        float s2 = 0.f;
        for (int k = 0; k < D_IN; ++k) s2 += rf[k] * rel_w[k * 50 + f];
        r2[f] = s2;
    }
    __syncthreads();
    if (tid < 50) {
        int f = tid;
        float a = 0.f;
        for (int b = 0; b < 5; ++b) {
            float cb = comp2[t * 5 + b];
            float s = 0.f;
            for (int k = 0; k < 50; ++k) s += r2[k] * basis2[(b * 50 + k) * 50 + f];
            a += cb * s;
        }
        rt2[t * 50 + f] = a;
    }
}

// ---- MFMA GEMM: Y[M, YROW] = X[M, KP] @ Wb (fragment-packed W, KP x 320).
// Block: 64 rows x 320 cols, 4 waves; wave w = rows [w*16, w*16+16), 20 col-tiles.
template<int KP>
__global__ __launch_bounds__(256) void k_gemm_mfma(const bf16* __restrict__ X,
                                                   const bf16* __restrict__ Wb,
                                                   bf16* __restrict__ Y, int M) {
    __shared__ bf16 smem[64 * 320];   // 40 KB; first 64*KP entries = X tile during K-loop
    int tid = threadIdx.x;
    int w = tid >> 6, lane = tid & 63;
    int quad = lane >> 4, cIn = lane & 15;
    int base_row = blockIdx.x * 64;

    const int TOT = 64 * KP / 8;
    for (int i = tid; i < TOT; i += 256) {
        int e8 = i * 8;
        int r = e8 / KP, c = e8 - r * KP;
        int row = base_row + r; if (row > M - 1) row = M - 1;
        *(uint4*)(&smem[r * KP + c]) = *(const uint4*)(&X[(size_t)row * KP + c]);
    }
    __syncthreads();

    f32x4 acc[20];
#pragma unroll
    for (int i = 0; i < 20; ++i) acc[i] = (f32x4){0.f, 0.f, 0.f, 0.f};

#pragma unroll
    for (int ks = 0; ks < KP / 32; ++ks) {
        short8 a = *(const short8*)(&smem[(w * 16 + cIn) * KP + ks * 32 + quad * 8]);
#pragma unroll
        for (int ct = 0; ct < 20; ++ct) {
            short8 b = *(const short8*)(&Wb[(size_t)((ks * 20 + ct) * 64 + lane) * 8]);
            acc[ct] = __builtin_amdgcn_mfma_f32_16x16x32_bf16(a, b, acc[ct], 0, 0, 0);
        }
    }
    __syncthreads();

#pragma unroll
    for (int ct = 0; ct < 20; ++ct)
#pragma unroll
        for (int r = 0; r < 4; ++r)
            smem[(w * 16 + quad * 4 + r) * 320 + ct * 16 + cIn] = f2b(acc[ct][r]);
    __syncthreads();

    int valid = M - base_row; if (valid > 64) valid = 64;
    int nchunk = valid * 40;   // 16B chunks: 320 bf16/row = 40
    uint4* dst = (uint4*)(Y + (size_t)base_row * 320);
    const uint4* s4 = (const uint4*)smem;
    for (int i = tid; i < nchunk; i += 256) dst[i] = s4[i];
}

// ---- zero Y row of target node (x[target]=0; Y is linear in x)
__global__ void k_zerorow(bf16* __restrict__ Y, const int* __restrict__ tgt) {
    int t = tgt[0];
    int i = threadIdx.x;
    if (i < YROW) Y[(size_t)t * YROW + i] = f2b(0.f);
}

// ================= CSR build ==========
__global__ void k_hist(const int* __restrict__ dst, int* __restrict__ cntI, int E) {
    int e = blockIdx.x * blockDim.x + threadIdx.x;
    if (e < E) atomicAdd(&cntI[dst[e]], 1);
}

__global__ void k_s1(const int* __restrict__ cntI, int* __restrict__ bsum) {
    __shared__ int sh[256];
    int i = blockIdx.x * 256 + threadIdx.x;
    sh[threadIdx.x] = (i < N_NODES) ? cntI[i] : 0;
    __syncthreads();
    for (int s = 128; s > 0; s >>= 1) {
        if (threadIdx.x < s) sh[threadIdx.x] += sh[threadIdx.x + s];
        __syncthreads();
    }
    if (threadIdx.x == 0) bsum[blockIdx.x] = sh[0];
}

// single-wave shuffle exclusive scan over NBLK block sums
__global__ void k_s2(int* __restrict__ bsum) {
    int lane = threadIdx.x;   // 64
    int carry = 0;
    for (int c = 0; c < (NBLK + 63) / 64; ++c) {
        int idx = c * 64 + lane;
        int v = (idx < NBLK) ? bsum[idx] : 0;
        int orig = v;
        for (int o = 1; o < 64; o <<= 1) {
            int t = __shfl_up(v, o);
            if (lane >= o) v += t;
        }
        if (idx < NBLK) bsum[idx] = carry + v - orig;
        carry += __shfl(v, 63);
    }
}

__global__ void k_s3(const int* __restrict__ cntI, const int* __restrict__ bsum,
                     int* __restrict__ off) {
    __shared__ int sh[256];
    int i = blockIdx.x * 256 + threadIdx.x;
    int v = (i < N_NODES) ? cntI[i] : 0;
    sh[threadIdx.x] = v;
    __syncthreads();
    for (int s = 1; s < 256; s <<= 1) {
        int t = (threadIdx.x >= (unsigned)s) ? sh[threadIdx.x - s] : 0;
        __syncthreads();
        sh[threadIdx.x] += t;
        __syncthreads();
    }
    int excl = sh[threadIdx.x] - v + bsum[blockIdx.x];
    if (i < N_NODES) off[i] = excl;
    if (i == N_NODES - 1) off[N_NODES] = excl + v;
}

__global__ void k_scatter(const int* __restrict__ src, const int* __restrict__ dst,
                          const int* __restrict__ et, const int* __restrict__ off,
                          int* __restrict__ fill, unsigned int* __restrict__ se, int E) {
    int e = blockIdx.x * blockDim.x + threadIdx.x;
    if (e >= E) return;
    int d = dst[e];
    int pos = off[d] + atomicAdd(&fill[d], 1);
    se[pos] = (unsigned int)src[e] | ((unsigned int)et[e] << 17);
}

// ================= per-node gather-reduce (no atomics) =======================
#define EDGE_BODY(p, ACC)                                                     \
    {                                                                         \
        int s_ = __builtin_amdgcn_readfirstlane((int)((p) & 0x1FFFFu));       \
        int t_ = __builtin_amdgcn_readfirstlane((int)((p) >> 17));            \
        const bf16* yr_ = Y + (size_t)s_ * YROW;                              \
        float a_ = rt[t_ * 50 + f];                                           \
        _Pragma("unroll")                                                     \
        for (int b_ = 0; b_ < 5; ++b_)                                        \
            a_ += comp[t_ * 5 + b_] * b2f(yr_[b_ * 50 + f]);                  \
        ACC += a_;                                                            \
    }

// Layer 1: h[row][0..63] = mean_agg + x@root (Y cols 250..299) + bias (cols>=50 zero)
__global__ __launch_bounds__(256) void k_reduce1(const int* __restrict__ off,
                                                 const unsigned int* __restrict__ se,
                                                 const float* __restrict__ comp,
                                                 const float* __restrict__ rt,
                                                 const bf16* __restrict__ Y,
                                                 const float* __restrict__ bias_,
                                                 bf16* __restrict__ h) {
    int wid = threadIdx.x >> 6, lane = threadIdx.x & 63;
    int row = blockIdx.x * 4 + wid;
    if (row >= N_NODES) return;
    int e0 = off[row], e1 = off[row + 1];
    int f = (lane < 50) ? lane : 49;
    float acc = 0.f;
    int e = e0;
    for (; e + 4 <= e1; e += 4) {
        unsigned p0 = se[e], p1 = se[e + 1], p2 = se[e + 2], p3 = se[e + 3];
        float a4 = 0.f;
        EDGE_BODY(p0, a4) EDGE_BODY(p1, a4) EDGE_BODY(p2, a4) EDGE_BODY(p3, a4)
        acc += a4;
    }
    for (; e < e1; ++e) {
        unsigned p = se[e];
        EDGE_BODY(p, acc)
    }
    float c = (float)(e1 - e0); c = c > 1.f ? c : 1.f;
    float v = acc / c + b2f(Y[(size_t)row * YROW + 250 + f]) + bias_[f];
    h[(size_t)row * 64 + lane] = f2b(lane < 50 ? v : 0.f);
}

// Layer 2: same reduce + log_softmax epilogue; dual-dtype output store.
__global__ __launch_bounds__(256) void k_reduce2(const int* __restrict__ off,
                                                 const unsigned int* __restrict__ se,
                                                 const float* __restrict__ comp,
                                                 const float* __restrict__ rt,
                                                 const bf16* __restrict__ Y,
                                                 const float* __restrict__ bias_,
                                                 const int* __restrict__ flag,
                                                 void* __restrict__ out) {
    int wid = threadIdx.x >> 6, lane = threadIdx.x & 63;
    int row = blockIdx.x * 4 + wid;
    if (row >= N_NODES) return;
    int e0 = off[row], e1 = off[row + 1];
    int f = (lane < 50) ? lane : 49;
    float acc = 0.f;
    int e = e0;
    for (; e + 4 <= e1; e += 4) {
        unsigned p0 = se[e], p1 = se[e + 1], p2 = se[e + 2], p3 = se[e + 3];
        float a4 = 0.f;
        EDGE_BODY(p0, a4) EDGE_BODY(p1, a4) EDGE_BODY(p2, a4) EDGE_BODY(p3, a4)
        acc += a4;
    }
    for (; e < e1; ++e) {
        unsigned p = se[e];
        EDGE_BODY(p, acc)
    }
    float c = (float)(e1 - e0); c = c > 1.f ? c : 1.f;
    float v = -INFINITY;
    if (lane < 50)
        v = acc / c + b2f(Y[(size_t)row * YROW + 250 + f]) + bias_[f];
    float m = v;
    for (int o = 32; o > 0; o >>= 1) m = fmaxf(m, __shfl_xor(m, o));
    float ex = (lane < 50) ? expf(v - m) : 0.f;
    float s = ex;
    for (int o = 32; o > 0; o >>= 1) s += __shfl_xor(s, o);
    float res = v - m - logf(s);
    if (lane < 50) {
        if (flag[0]) ((bf16*)out)[row * 50 + f] = f2b(res);
        else         ((float*)out)[row * 50 + f] = res;
    }
}

extern "C" void kernel_launch(void* const* d_in, const int* in_sizes, int n_in,
                              void* d_out, int out_size, void* d_ws, size_t ws_size,
                              hipStream_t stream) {
    const void* x_raw = d_in[0];
    const int*  ei    = (const int*)d_in[1];
    const int*  et    = (const int*)d_in[2];
    const int*  tgt   = (const int*)d_in[3];

    char* wsp = (char*)d_ws;
    size_t off_b = 0;
    auto alloc = [&](size_t bytes) {
        void* p = wsp + off_b;
        off_b = (off_b + bytes + 255) & ~(size_t)255;
        return p;
    };
    bf16*  Y    = (bf16*) alloc((size_t)N_NODES * YROW * sizeof(bf16));      // 64 MB
    bf16*  xc   = (bf16*) alloc((size_t)N_NODES * 128 * sizeof(bf16));       // 25.6 MB
    bf16*  h    = xc;   // alias: xc dead after layer-1 GEMM; h is [N_NODES][64]
    unsigned int* se = (unsigned int*)alloc((size_t)N_EDGES * sizeof(unsigned int));
    int*   cntI = (int*)  alloc((size_t)N_NODES * sizeof(int));
    int*   offs = (int*)  alloc((size_t)(N_NODES + 1) * sizeof(int));
    int*   fill = (int*)  alloc((size_t)N_NODES * sizeof(int));
    int*   bsum = (int*)  alloc((size_t)NBLK * sizeof(int));
    float* wc   = (float*)alloc((size_t)W_TOTAL * sizeof(float));
    bf16*  Wb1  = (bf16*) alloc((size_t)40960 * sizeof(bf16));   // 4 ksteps x 10240
    bf16*  Wb2  = (bf16*) alloc((size_t)20480 * sizeof(bf16));   // 2 ksteps x 10240
    float* rt1  = (float*)alloc((size_t)N_REL2 * 50 * sizeof(float));
    float* rt2  = (float*)alloc((size_t)N_REL2 * 50 * sizeof(float));
    int*   flag = (int*)  alloc(sizeof(int));

    const int* srcp = ei;
    const int* dstp = ei + N_EDGES;

    hipMemsetAsync(cntI, 0, (size_t)N_NODES * sizeof(int), stream);
    hipMemsetAsync(fill, 0, (size_t)N_NODES * sizeof(int), stream);

    // dtype detect + canonicalize
    k_detect<<<1, 256, 0, stream>>>((const unsigned short*)x_raw, flag);
    k_convert_x<<<(N_NODES * 128 + 255) / 256, 256, 0, stream>>>(x_raw, flag, xc);
    WPtrs wp;
    for (int i = 0; i < 10; ++i) wp.p[i] = d_in[4 + i];
    k_convert_w<<<(W_TOTAL + 255) / 256, 256, 0, stream>>>(wp, flag, wc);

    k_pack_mfma<<<160, 256, 0, stream>>>(wc + O_BASIS1, wc + O_ROOT1, Wb1, D_IN, 128);
    k_pack_mfma<<<80, 256, 0, stream>>>(wc + O_BASIS2, wc + O_ROOT2, Wb2, D_HID, 64);
    k_rel<<<N_REL2, 64, 0, stream>>>(wc, rt1, rt2);

    // CSR build (graph shared by both layers)
    k_hist<<<(N_EDGES + 255) / 256, 256, 0, stream>>>(dstp, cntI, N_EDGES);
    k_s1<<<NBLK, 256, 0, stream>>>(cntI, bsum);
    k_s2<<<1, 64, 0, stream>>>(bsum);
    k_s3<<<NBLK, 256, 0, stream>>>(cntI, bsum, offs);
    k_scatter<<<(N_EDGES + 255) / 256, 256, 0, stream>>>(srcp, dstp, et, offs, fill, se, N_EDGES);

    // Layer 1
    k_gemm_mfma<128><<<(N_NODES + 63) / 64, 256, 0, stream>>>(xc, Wb1, Y, N_NODES);
    k_zerorow<<<1, 320, 0, stream>>>(Y, tgt);
    k_reduce1<<<(N_NODES + 3) / 4, 256, 0, stream>>>(offs, se, wc + O_COMP1, rt1, Y, wc + O_BIAS1, h);

    // Layer 2
    k_gemm_mfma<64><<<(N_NODES + 63) / 64, 256, 0, stream>>>(h, Wb2, Y, N_NODES);
    k_reduce2<<<(N_NODES + 3) / 4, 256, 0, stream>>>(offs, se, wc + O_COMP2, rt2, Y, wc + O_BIAS2, flag, d_out);
}

// Round 5
// 646.275 us; speedup vs baseline: 4.0917x; 1.0295x over previous
//
#include <hip/hip_runtime.h>
#include <hip/hip_bf16.h>

typedef __hip_bfloat16 bf16;

#define N_NODES 100000
#define N_EDGES 1600000
#define D_IN    100
#define D_HID   50
#define N_REL   237
#define N_REL2  474
#define N_CLASS 50
#define YROW    320   // padded Y row stride: 250 basis + 50 root + 20 pad
#define NBLK    391   // ceil(N_NODES/256)

// Canonical fp32 weight-block offsets (element offsets into wc)
#define O_RELEMB 0
#define O_RELW   23700
#define O_BASIS1 28700
#define O_COMP1  53700
#define O_ROOT1  56070
#define O_BIAS1  61070
#define O_BASIS2 61120
#define O_COMP2  73620
#define O_ROOT2  75990
#define O_BIAS2  78490
#define W_TOTAL  78540

// prep1 grid partition (256-thread blocks)
#define P1_CVTX_BLKS 50000            // N_NODES*128/256
#define P1_CVTW_BLKS 307              // ceil(W_TOTAL/256)
#define P1_HIST_BLKS 6250             // N_EDGES/256
#define P1_TOTAL (P1_CVTX_BLKS + P1_CVTW_BLKS + P1_HIST_BLKS)

// prep2 grid partition
#define P2_PACK1_BLKS 160             // 4 ksteps * 10240 / 256
#define P2_PACK2_BLKS 80
#define P2_REL_BLKS   474
#define P2_S1_BLKS    NBLK
#define P2_TOTAL (P2_PACK1_BLKS + P2_PACK2_BLKS + P2_REL_BLKS + P2_S1_BLKS)

typedef __attribute__((ext_vector_type(8))) short short8;
typedef __attribute__((ext_vector_type(4))) float f32x4;

__device__ __forceinline__ float b2f(bf16 v) { return __bfloat162float(v); }
__device__ __forceinline__ bf16  f2b(float v) { return __float2bfloat16(v); }

// ---- dtype detection: flag[0]=1 if float arrays are stored as bf16, 0 if fp32.
__global__ void k_detect(const unsigned short* __restrict__ xr, int* __restrict__ flag) {
    int tid = threadIdx.x;
    int cnt = 0;
    for (int i = tid; i < 4096; i += 256) {
        unsigned short u = xr[2 * i];
        unsigned e = (u >> 7) & 0xFF;
        bool pl = (e >= 107 && e <= 132) || ((u & 0x7FFF) == 0);
        cnt += pl ? 1 : 0;
    }
    __shared__ int sh[256];
    sh[tid] = cnt;
    __syncthreads();
    for (int s = 128; s > 0; s >>= 1) {
        if (tid < s) sh[tid] += sh[tid + s];
        __syncthreads();
    }
    if (tid == 0) flag[0] = (sh[0] >= 3072) ? 1 : 0;
}

struct WPtrs { const void* p[10]; };

// ================= fused prep1: convert_x | convert_w | hist =================
__global__ __launch_bounds__(256) void k_prep1(const void* __restrict__ xr,
                                               const int* __restrict__ flag,
                                               bf16* __restrict__ xc,
                                               WPtrs wp, float* __restrict__ wc,
                                               const int* __restrict__ dstp,
                                               int* __restrict__ cntI) {
    int blk = blockIdx.x;
    if (blk < P1_CVTX_BLKS) {
        int g = blk * 256 + threadIdx.x;
        int row = g >> 7, col = g & 127;
        bf16 o = f2b(0.f);
        if (col < D_IN) {
            if (flag[0]) o = ((const bf16*)xr)[row * D_IN + col];
            else         o = f2b(((const float*)xr)[row * D_IN + col]);
        }
        xc[g] = o;
        return;
    }
    blk -= P1_CVTX_BLKS;
    if (blk < P1_CVTW_BLKS) {
        const int sz[10] = {23700, 5000, 25000, 2370, 5000, 50, 12500, 2370, 2500, 50};
        int g = blk * 256 + threadIdx.x;
        if (g >= W_TOTAL) return;
        int j = 0, base = 0;
        while (j < 9 && g >= base + sz[j]) { base += sz[j]; ++j; }
        int idx = g - base;
        float v;
        if (flag[0]) v = b2f(((const bf16*)wp.p[j])[idx]);
        else         v = ((const float*)wp.p[j])[idx];
        wc[g] = v;
        return;
    }
    blk -= P1_CVTW_BLKS;
    {
        int e = blk * 256 + threadIdx.x;
        if (e < N_EDGES) atomicAdd(&cntI[dstp[e]], 1);
    }
}

// ---- pack job body: basis[5][KL][50] + root[KL][50] -> MFMA B-fragment order
__device__ __forceinline__ void job_pack(int blk, const float* basis, const float* root,
                                         bf16* Wb, int KL) {
    int g = blk * 256 + threadIdx.x;
    int ks = g / 10240;
    int r = g - ks * 10240;
    int ct = r >> 9;
    int r2 = r & 511;
    int l = r2 >> 3, j = r2 & 7;
    int k = ks * 32 + ((l >> 4) << 3) + j;
    int n = ct * 16 + (l & 15);
    float v = 0.f;
    if (k < KL && n < 300) {
        if (n < 250) { int b = n / 50, f = n - b * 50; v = basis[(b * KL + k) * 50 + f]; }
        else         v = root[k * 50 + (n - 250)];
    }
    Wb[g] = f2b(v);
}

// ================= fused prep2: pack1 | pack2 | rel | s1 =====================
__global__ __launch_bounds__(256) void k_prep2(const float* __restrict__ wc,
                                               bf16* __restrict__ Wb1, bf16* __restrict__ Wb2,
                                               bf16* __restrict__ rt1, bf16* __restrict__ rt2,
                                               const int* __restrict__ cntI,
                                               int* __restrict__ bsum) {
    int blk = blockIdx.x;
    if (blk < P2_PACK1_BLKS) { job_pack(blk, wc + O_BASIS1, wc + O_ROOT1, Wb1, D_IN); return; }
    blk -= P2_PACK1_BLKS;
    if (blk < P2_PACK2_BLKS) { job_pack(blk, wc + O_BASIS2, wc + O_ROOT2, Wb2, D_HID); return; }
    blk -= P2_PACK2_BLKS;
    if (blk < P2_REL_BLKS) {
        // per-relation constant terms, one relation per block
        const float* rel_emb = wc + O_RELEMB;
        const float* rel_w   = wc + O_RELW;
        const float* basis1  = wc + O_BASIS1;
        const float* comp1   = wc + O_COMP1;
        const float* basis2  = wc + O_BASIS2;
        const float* comp2   = wc + O_COMP2;
        int t = blk;
        int tid = threadIdx.x;
        __shared__ float rf[D_IN];
        __shared__ float r2s[D_HID];
        int tm = (t >= N_REL) ? t - N_REL : t;
        if (tid < D_IN) rf[tid] = rel_emb[tm * D_IN + tid];
        __syncthreads();
        if (tid < 50) {
            int f = tid;
            float a = 0.f;
            for (int b = 0; b < 5; ++b) {
                float cb = comp1[t * 5 + b];
                float s = 0.f;
                for (int k = 0; k < D_IN; ++k) s += rf[k] * basis1[(b * D_IN + k) * 50 + f];
                a += cb * s;
            }
            rt1[t * 50 + f] = f2b(a);
            float s2 = 0.f;
            for (int k = 0; k < D_IN; ++k) s2 += rf[k] * rel_w[k * 50 + f];
            r2s[f] = s2;
        }
        __syncthreads();
        if (tid < 50) {
            int f = tid;
            float a = 0.f;
            for (int b = 0; b < 5; ++b) {
                float cb = comp2[t * 5 + b];
                float s = 0.f;
                for (int k = 0; k < 50; ++k) s += r2s[k] * basis2[(b * 50 + k) * 50 + f];
                a += cb * s;
            }
            rt2[t * 50 + f] = f2b(a);
        }
        return;
    }
    blk -= P2_REL_BLKS;
    {
        // s1: per-256-node block sums of cntI
        __shared__ int sh[256];
        int i = blk * 256 + threadIdx.x;
        sh[threadIdx.x] = (i < N_NODES) ? cntI[i] : 0;
        __syncthreads();
        for (int s = 128; s > 0; s >>= 1) {
            if (threadIdx.x < s) sh[threadIdx.x] += sh[threadIdx.x + s];
            __syncthreads();
        }
        if (threadIdx.x == 0) bsum[blk] = sh[0];
    }
}

// single-wave shuffle exclusive scan over NBLK block sums
__global__ void k_s2(int* __restrict__ bsum) {
    int lane = threadIdx.x;   // 64
    int carry = 0;
    for (int c = 0; c < (NBLK + 63) / 64; ++c) {
        int idx = c * 64 + lane;
        int v = (idx < NBLK) ? bsum[idx] : 0;
        int orig = v;
        for (int o = 1; o < 64; o <<= 1) {
            int t = __shfl_up(v, o);
            if (lane >= o) v += t;
        }
        if (idx < NBLK) bsum[idx] = carry + v - orig;
        carry += __shfl(v, 63);
    }
}

__global__ void k_s3(const int* __restrict__ cntI, const int* __restrict__ bsum,
                     int* __restrict__ off) {
    __shared__ int sh[256];
    int i = blockIdx.x * 256 + threadIdx.x;
    int v = (i < N_NODES) ? cntI[i] : 0;
    sh[threadIdx.x] = v;
    __syncthreads();
    for (int s = 1; s < 256; s <<= 1) {
        int t = (threadIdx.x >= (unsigned)s) ? sh[threadIdx.x - s] : 0;
        __syncthreads();
        sh[threadIdx.x] += t;
        __syncthreads();
    }
    int excl = sh[threadIdx.x] - v + bsum[blockIdx.x];
    if (i < N_NODES) off[i] = excl;
    if (i == N_NODES - 1) off[N_NODES] = excl + v;
}

__global__ void k_scatter(const int* __restrict__ src, const int* __restrict__ dst,
                          const int* __restrict__ et, const int* __restrict__ off,
                          int* __restrict__ fill, unsigned int* __restrict__ se, int E) {
    int e = blockIdx.x * blockDim.x + threadIdx.x;
    if (e >= E) return;
    int d = dst[e];
    int pos = off[d] + atomicAdd(&fill[d], 1);
    se[pos] = (unsigned int)src[e] | ((unsigned int)et[e] << 17);
}

// ---- MFMA GEMM: Y[M, YROW] = X[M, KP] @ Wb (fragment-packed W, KP x 320).
// ZT: zero the target node's output row (layer 1 only; x[target]=0, Y linear in x).
template<int KP, bool ZT>
__global__ __launch_bounds__(256) void k_gemm_mfma(const bf16* __restrict__ X,
                                                   const bf16* __restrict__ Wb,
                                                   bf16* __restrict__ Y, int M,
                                                   const int* __restrict__ tgt) {
    __shared__ bf16 smem[64 * 320];   // 40 KB
    int tid = threadIdx.x;
    int w = tid >> 6, lane = tid & 63;
    int quad = lane >> 4, cIn = lane & 15;
    int base_row = blockIdx.x * 64;

    const int TOT = 64 * KP / 8;
    for (int i = tid; i < TOT; i += 256) {
        int e8 = i * 8;
        int r = e8 / KP, c = e8 - r * KP;
        int row = base_row + r; if (row > M - 1) row = M - 1;
        *(uint4*)(&smem[r * KP + c]) = *(const uint4*)(&X[(size_t)row * KP + c]);
    }
    __syncthreads();

    f32x4 acc[20];
#pragma unroll
    for (int i = 0; i < 20; ++i) acc[i] = (f32x4){0.f, 0.f, 0.f, 0.f};

#pragma unroll
    for (int ks = 0; ks < KP / 32; ++ks) {
        short8 a = *(const short8*)(&smem[(w * 16 + cIn) * KP + ks * 32 + quad * 8]);
#pragma unroll
        for (int ct = 0; ct < 20; ++ct) {
            short8 b = *(const short8*)(&Wb[(size_t)((ks * 20 + ct) * 64 + lane) * 8]);
            acc[ct] = __builtin_amdgcn_mfma_f32_16x16x32_bf16(a, b, acc[ct], 0, 0, 0);
        }
    }
    __syncthreads();

#pragma unroll
    for (int ct = 0; ct < 20; ++ct)
#pragma unroll
        for (int r = 0; r < 4; ++r)
            smem[(w * 16 + quad * 4 + r) * 320 + ct * 16 + cIn] = f2b(acc[ct][r]);
    __syncthreads();

    int tv = -1;
    if (ZT) tv = tgt[0];
    int valid = M - base_row; if (valid > 64) valid = 64;
    int nchunk = valid * 40;   // 16B chunks: 320 bf16/row = 40
    uint4* dst = (uint4*)(Y + (size_t)base_row * 320);
    const uint4* s4 = (const uint4*)smem;
    for (int i = tid; i < nchunk; i += 256) {
        uint4 v = s4[i];
        if (ZT && (base_row + i / 40) == tv) v = (uint4){0u, 0u, 0u, 0u};
        dst[i] = v;
    }
}

// ================= per-node gather-reduce (no atomics) =======================
#define EDGE_BODY(p, ACC)                                                     \
    {                                                                         \
        int s_ = __builtin_amdgcn_readfirstlane((int)((p) & 0x1FFFFu));       \
        int t_ = __builtin_amdgcn_readfirstlane((int)((p) >> 17));            \
        const bf16* yr_ = Y + (size_t)s_ * YROW;                              \
        float a_ = b2f(rt[t_ * 50 + f]);                                      \
        _Pragma("unroll")                                                     \
        for (int b_ = 0; b_ < 5; ++b_)                                        \
            a_ += comp[t_ * 5 + b_] * b2f(yr_[b_ * 50 + f]);                  \
        ACC += a_;                                                            \
    }

#define REDUCE_LOOP                                                           \
    float acc = 0.f;                                                          \
    int e = e0;                                                               \
    for (; e + 8 <= e1; e += 8) {                                             \
        unsigned p0 = se[e],     p1 = se[e + 1], p2 = se[e + 2], p3 = se[e + 3]; \
        unsigned p4 = se[e + 4], p5 = se[e + 5], p6 = se[e + 6], p7 = se[e + 7]; \
        float a8 = 0.f;                                                       \
        EDGE_BODY(p0, a8) EDGE_BODY(p1, a8) EDGE_BODY(p2, a8) EDGE_BODY(p3, a8) \
        EDGE_BODY(p4, a8) EDGE_BODY(p5, a8) EDGE_BODY(p6, a8) EDGE_BODY(p7, a8) \
        acc += a8;                                                            \
    }                                                                         \
    for (; e < e1; ++e) {                                                     \
        unsigned p = se[e];                                                   \
        EDGE_BODY(p, acc)                                                     \
    }

// Layer 1: h[row][0..63] = mean_agg + x@root (Y cols 250..299) + bias (cols>=50 zero)
__global__ __launch_bounds__(256) void k_reduce1(const int* __restrict__ off,
                                                 const unsigned int* __restrict__ se,
                                                 const float* __restrict__ comp,
                                                 const bf16* __restrict__ rt,
                                                 const bf16* __restrict__ Y,
                                                 const float* __restrict__ bias_,
                                                 bf16* __restrict__ h) {
    int wid = threadIdx.x >> 6, lane = threadIdx.x & 63;
    int row = blockIdx.x * 4 + wid;
    if (row >= N_NODES) return;
    int e0 = off[row], e1 = off[row + 1];
    int f = (lane < 50) ? lane : 49;
    REDUCE_LOOP
    float c = (float)(e1 - e0); c = c > 1.f ? c : 1.f;
    float v = acc / c + b2f(Y[(size_t)row * YROW + 250 + f]) + bias_[f];
    h[(size_t)row * 64 + lane] = f2b(lane < 50 ? v : 0.f);
}

// Layer 2: same reduce + log_softmax epilogue; dual-dtype output store.
__global__ __launch_bounds__(256) void k_reduce2(const int* __restrict__ off,
                                                 const unsigned int* __restrict__ se,
                                                 const float* __restrict__ comp,
                                                 const bf16* __restrict__ rt,
                                                 const bf16* __restrict__ Y,
                                                 const float* __restrict__ bias_,
                                                 const int* __restrict__ flag,
                                                 void* __restrict__ out) {
    int wid = threadIdx.x >> 6, lane = threadIdx.x & 63;
    int row = blockIdx.x * 4 + wid;
    if (row >= N_NODES) return;
    int e0 = off[row], e1 = off[row + 1];
    int f = (lane < 50) ? lane : 49;
    REDUCE_LOOP
    float c = (float)(e1 - e0); c = c > 1.f ? c : 1.f;
    float v = -INFINITY;
    if (lane < 50)
        v = acc / c + b2f(Y[(size_t)row * YROW + 250 + f]) + bias_[f];
    float m = v;
    for (int o = 32; o > 0; o >>= 1) m = fmaxf(m, __shfl_xor(m, o));
    float ex = (lane < 50) ? expf(v - m) : 0.f;
    float s = ex;
    for (int o = 32; o > 0; o >>= 1) s += __shfl_xor(s, o);
    float res = v - m - logf(s);
    if (lane < 50) {
        if (flag[0]) ((bf16*)out)[row * 50 + f] = f2b(res);
        else         ((float*)out)[row * 50 + f] = res;
    }
}

extern "C" void kernel_launch(void* const* d_in, const int* in_sizes, int n_in,
                              void* d_out, int out_size, void* d_ws, size_t ws_size,
                              hipStream_t stream) {
    const void* x_raw = d_in[0];
    const int*  ei    = (const int*)d_in[1];
    const int*  et    = (const int*)d_in[2];
    const int*  tgt   = (const int*)d_in[3];

    char* wsp = (char*)d_ws;
    size_t off_b = 0;
    auto alloc = [&](size_t bytes) {
        void* p = wsp + off_b;
        off_b = (off_b + bytes + 255) & ~(size_t)255;
        return p;
    };
    bf16*  Y    = (bf16*) alloc((size_t)N_NODES * YROW * sizeof(bf16));      // 64 MB
    bf16*  xc   = (bf16*) alloc((size_t)N_NODES * 128 * sizeof(bf16));       // 25.6 MB
    bf16*  h    = xc;   // alias: xc dead after layer-1 GEMM; h is [N_NODES][64]
    unsigned int* se = (unsigned int*)alloc((size_t)N_EDGES * sizeof(unsigned int));
    int*   cntI = (int*)  alloc((size_t)N_NODES * sizeof(int));
    int*   offs = (int*)  alloc((size_t)(N_NODES + 1) * sizeof(int));
    int*   fill = (int*)  alloc((size_t)N_NODES * sizeof(int));
    int*   bsum = (int*)  alloc((size_t)NBLK * sizeof(int));
    float* wc   = (float*)alloc((size_t)W_TOTAL * sizeof(float));
    bf16*  Wb1  = (bf16*) alloc((size_t)40960 * sizeof(bf16));   // 4 ksteps x 10240
    bf16*  Wb2  = (bf16*) alloc((size_t)20480 * sizeof(bf16));   // 2 ksteps x 10240
    bf16*  rt1  = (bf16*) alloc((size_t)N_REL2 * 50 * sizeof(bf16));
    bf16*  rt2  = (bf16*) alloc((size_t)N_REL2 * 50 * sizeof(bf16));
    int*   flag = (int*)  alloc(sizeof(int));

    const int* srcp = ei;
    const int* dstp = ei + N_EDGES;

    hipMemsetAsync(cntI, 0, (size_t)N_NODES * sizeof(int), stream);
    hipMemsetAsync(fill, 0, (size_t)N_NODES * sizeof(int), stream);

    WPtrs wp;
    for (int i = 0; i < 10; ++i) wp.p[i] = d_in[4 + i];

    k_detect<<<1, 256, 0, stream>>>((const unsigned short*)x_raw, flag);
    k_prep1<<<P1_TOTAL, 256, 0, stream>>>(x_raw, flag, xc, wp, wc, dstp, cntI);
    k_prep2<<<P2_TOTAL, 256, 0, stream>>>(wc, Wb1, Wb2, rt1, rt2, cntI, bsum);
    k_s2<<<1, 64, 0, stream>>>(bsum);
    k_s3<<<NBLK, 256, 0, stream>>>(cntI, bsum, offs);
    k_scatter<<<(N_EDGES + 255) / 256, 256, 0, stream>>>(srcp, dstp, et, offs, fill, se, N_EDGES);

    // Layer 1
    k_gemm_mfma<128, true><<<(N_NODES + 63) / 64, 256, 0, stream>>>(xc, Wb1, Y, N_NODES, tgt);
    k_reduce1<<<(N_NODES + 3) / 4, 256, 0, stream>>>(offs, se, wc + O_COMP1, rt1, Y, wc + O_BIAS1, h);

    // Layer 2
    k_gemm_mfma<64, false><<<(N_NODES + 63) / 64, 256, 0, stream>>>(h, Wb2, Y, N_NODES, nullptr);
    k_reduce2<<<(N_NODES + 3) / 4, 256, 0, stream>>>(offs, se, wc + O_COMP2, rt2, Y, wc + O_BIAS2, flag, d_out);
}

// Round 6
// 594.779 us; speedup vs baseline: 4.4460x; 1.0866x over previous
//
#include <hip/hip_runtime.h>
#include <hip/hip_bf16.h>

typedef __hip_bfloat16 bf16;

#define N_NODES 100000
#define N_EDGES 1600000
#define D_IN    100
#define D_HID   50
#define N_REL   237
#define N_REL2  474
#define N_CLASS 50
#define NBLK    391   // ceil(N_NODES/256)

// Canonical fp32 weight-block offsets (element offsets into wc)
#define O_RELEMB 0
#define O_RELW   23700
#define O_BASIS1 28700
#define O_COMP1  53700
#define O_ROOT1  56070
#define O_BIAS1  61070
#define O_BASIS2 61120
#define O_COMP2  73620
#define O_ROOT2  75990
#define O_BIAS2  78490
#define W_TOTAL  78540

// prep1 grid partition (256-thread blocks)
#define P1_CVTX_BLKS 50000            // N_NODES*128/256
#define P1_CVTW_BLKS 307              // ceil(W_TOTAL/256)
#define P1_HIST_BLKS 6250             // N_EDGES/256
#define P1_TOTAL (P1_CVTX_BLKS + P1_CVTW_BLKS + P1_HIST_BLKS)

// prep2 grid partition
#define P2_PACK1_BLKS 160             // 4 ksteps * 10240 / 256
#define P2_PACK2_BLKS 80
#define P2_REL_BLKS   474
#define P2_S1_BLKS    NBLK
#define P2_TOTAL (P2_PACK1_BLKS + P2_PACK2_BLKS + P2_REL_BLKS + P2_S1_BLKS)

typedef __attribute__((ext_vector_type(8))) short short8;
typedef __attribute__((ext_vector_type(4))) float f32x4;

__device__ __forceinline__ float b2f(bf16 v) { return __bfloat162float(v); }
__device__ __forceinline__ bf16  f2b(float v) { return __float2bfloat16(v); }

#if __has_builtin(__builtin_amdgcn_cvt_f32_fp8) && __has_builtin(__builtin_amdgcn_cvt_pk_fp8_f32)
#define F8_HW 1
#endif

// ---- fp8 e4m3 (OCP, gfx950 HW) helpers ----
__device__ __forceinline__ float f8tof(unsigned u) {
#ifdef F8_HW
    return __builtin_amdgcn_cvt_f32_fp8((int)u, 0);
#else
    unsigned s = u >> 7, e = (u >> 3) & 0xF, m = u & 7;
    float v;
    if (e == 0) v = (float)m * 0.001953125f;                       // m * 2^-9
    else        v = (float)(8 + m) * __builtin_ldexpf(1.f, (int)e - 10);
    return s ? -v : v;
#endif
}

__device__ __forceinline__ unsigned f8enc_sw(float v) {
    unsigned bits = __float_as_uint(v);
    unsigned s = bits >> 31;
    float a = fabsf(v);
    if (a < 0.0009765625f) return s << 7;
    if (a >= 448.f) return (s << 7) | 0x7E;
    int E = (int)((bits >> 23) & 0xFF) - 127;
    unsigned m = bits & 0x7FFFFF;
    if (E < -6) {
        int q = (int)rintf(a * 512.f);
        if (q > 7) q = 7;
        return (s << 7) | (unsigned)q;
    }
    unsigned lsb = (m >> 20) & 1, rnd = (m >> 19) & 1;
    unsigned sticky = (m & 0x7FFFF) ? 1u : 0u;
    unsigned m3 = (m >> 20) + (rnd & (sticky | lsb));
    if (m3 == 8) { m3 = 0; E += 1; }
    if (E > 8) return (s << 7) | 0x7E;
    return (s << 7) | ((unsigned)(E + 7) << 3) | m3;
}

__device__ __forceinline__ unsigned pk4_f8(float v0, float v1, float v2, float v3) {
#ifdef F8_HW
    int p = __builtin_amdgcn_cvt_pk_fp8_f32(v0, v1, 0, false);
    p = __builtin_amdgcn_cvt_pk_fp8_f32(v2, v3, p, true);
    return (unsigned)p;
#else
    return f8enc_sw(v0) | (f8enc_sw(v1) << 8) | (f8enc_sw(v2) << 16) | (f8enc_sw(v3) << 24);
#endif
}

// ---- dtype detection: flag[0]=1 if float arrays are stored as bf16, 0 if fp32.
__global__ void k_detect(const unsigned short* __restrict__ xr, int* __restrict__ flag) {
    int tid = threadIdx.x;
    int cnt = 0;
    for (int i = tid; i < 4096; i += 256) {
        unsigned short u = xr[2 * i];
        unsigned e = (u >> 7) & 0xFF;
        bool pl = (e >= 107 && e <= 132) || ((u & 0x7FFF) == 0);
        cnt += pl ? 1 : 0;
    }
    __shared__ int sh[256];
    sh[tid] = cnt;
    __syncthreads();
    for (int s = 128; s > 0; s >>= 1) {
        if (tid < s) sh[tid] += sh[tid + s];
        __syncthreads();
    }
    if (tid == 0) flag[0] = (sh[0] >= 3072) ? 1 : 0;
}

struct WPtrs { const void* p[10]; };

// ================= fused prep1: convert_x | convert_w | hist =================
__global__ __launch_bounds__(256) void k_prep1(const void* __restrict__ xr,
                                               const int* __restrict__ flag,
                                               bf16* __restrict__ xc,
                                               WPtrs wp, float* __restrict__ wc,
                                               const int* __restrict__ dstp,
                                               int* __restrict__ cntI) {
    int blk = blockIdx.x;
    if (blk < P1_CVTX_BLKS) {
        int g = blk * 256 + threadIdx.x;
        int row = g >> 7, col = g & 127;
        bf16 o = f2b(0.f);
        if (col < D_IN) {
            if (flag[0]) o = ((const bf16*)xr)[row * D_IN + col];
            else         o = f2b(((const float*)xr)[row * D_IN + col]);
        }
        xc[g] = o;
        return;
    }
    blk -= P1_CVTX_BLKS;
    if (blk < P1_CVTW_BLKS) {
        const int sz[10] = {23700, 5000, 25000, 2370, 5000, 50, 12500, 2370, 2500, 50};
        int g = blk * 256 + threadIdx.x;
        if (g >= W_TOTAL) return;
        int j = 0, base = 0;
        while (j < 9 && g >= base + sz[j]) { base += sz[j]; ++j; }
        int idx = g - base;
        float v;
        if (flag[0]) v = b2f(((const bf16*)wp.p[j])[idx]);
        else         v = ((const float*)wp.p[j])[idx];
        wc[g] = v;
        return;
    }
    blk -= P1_CVTW_BLKS;
    {
        int e = blk * 256 + threadIdx.x;
        if (e < N_EDGES) atomicAdd(&cntI[dstp[e]], 1);
    }
}

// ---- pack job body: basis[5][KL][50] + root[KL][50] -> MFMA B-fragment order
__device__ __forceinline__ void job_pack(int blk, const float* basis, const float* root,
                                         bf16* Wb, int KL) {
    int g = blk * 256 + threadIdx.x;
    int ks = g / 10240;
    int r = g - ks * 10240;
    int ct = r >> 9;
    int r2 = r & 511;
    int l = r2 >> 3, j = r2 & 7;
    int k = ks * 32 + ((l >> 4) << 3) + j;
    int n = ct * 16 + (l & 15);
    float v = 0.f;
    if (k < KL && n < 300) {
        if (n < 250) { int b = n / 50, f = n - b * 50; v = basis[(b * KL + k) * 50 + f]; }
        else         v = root[k * 50 + (n - 250)];
    }
    Wb[g] = f2b(v);
}

// ================= fused prep2: pack1 | pack2 | rel | s1 =====================
__global__ __launch_bounds__(256) void k_prep2(const float* __restrict__ wc,
                                               bf16* __restrict__ Wb1, bf16* __restrict__ Wb2,
                                               bf16* __restrict__ rt1, bf16* __restrict__ rt2,
                                               const int* __restrict__ cntI,
                                               int* __restrict__ bsum) {
    int blk = blockIdx.x;
    if (blk < P2_PACK1_BLKS) { job_pack(blk, wc + O_BASIS1, wc + O_ROOT1, Wb1, D_IN); return; }
    blk -= P2_PACK1_BLKS;
    if (blk < P2_PACK2_BLKS) { job_pack(blk, wc + O_BASIS2, wc + O_ROOT2, Wb2, D_HID); return; }
    blk -= P2_PACK2_BLKS;
    if (blk < P2_REL_BLKS) {
        const float* rel_emb = wc + O_RELEMB;
        const float* rel_w   = wc + O_RELW;
        const float* basis1  = wc + O_BASIS1;
        const float* comp1   = wc + O_COMP1;
        const float* basis2  = wc + O_BASIS2;
        const float* comp2   = wc + O_COMP2;
        int t = blk;
        int tid = threadIdx.x;
        __shared__ float rf[D_IN];
        __shared__ float r2s[D_HID];
        int tm = (t >= N_REL) ? t - N_REL : t;
        if (tid < D_IN) rf[tid] = rel_emb[tm * D_IN + tid];
        __syncthreads();
        if (tid < 50) {
            int f = tid;
            float a = 0.f;
            for (int b = 0; b < 5; ++b) {
                float cb = comp1[t * 5 + b];
                float s = 0.f;
                for (int k = 0; k < D_IN; ++k) s += rf[k] * basis1[(b * D_IN + k) * 50 + f];
                a += cb * s;
            }
            rt1[t * 50 + f] = f2b(a);
            float s2 = 0.f;
            for (int k = 0; k < D_IN; ++k) s2 += rf[k] * rel_w[k * 50 + f];
            r2s[f] = s2;
        }
        __syncthreads();
        if (tid < 50) {
            int f = tid;
            float a = 0.f;
            for (int b = 0; b < 5; ++b) {
                float cb = comp2[t * 5 + b];
                float s = 0.f;
                for (int k = 0; k < 50; ++k) s += r2s[k] * basis2[(b * 50 + k) * 50 + f];
                a += cb * s;
            }
            rt2[t * 50 + f] = f2b(a);
        }
        return;
    }
    blk -= P2_REL_BLKS;
    {
        __shared__ int sh[256];
        int i = blk * 256 + threadIdx.x;
        sh[threadIdx.x] = (i < N_NODES) ? cntI[i] : 0;
        __syncthreads();
        for (int s = 128; s > 0; s >>= 1) {
            if (threadIdx.x < s) sh[threadIdx.x] += sh[threadIdx.x + s];
            __syncthreads();
        }
        if (threadIdx.x == 0) bsum[blk] = sh[0];
    }
}

// single-wave shuffle exclusive scan over NBLK block sums
__global__ void k_s2(int* __restrict__ bsum) {
    int lane = threadIdx.x;   // 64
    int carry = 0;
    for (int c = 0; c < (NBLK + 63) / 64; ++c) {
        int idx = c * 64 + lane;
        int v = (idx < NBLK) ? bsum[idx] : 0;
        int orig = v;
        for (int o = 1; o < 64; o <<= 1) {
            int t = __shfl_up(v, o);
            if (lane >= o) v += t;
        }
        if (idx < NBLK) bsum[idx] = carry + v - orig;
        carry += __shfl(v, 63);
    }
}

__global__ void k_s3(const int* __restrict__ cntI, const int* __restrict__ bsum,
                     int* __restrict__ off) {
    __shared__ int sh[256];
    int i = blockIdx.x * 256 + threadIdx.x;
    int v = (i < N_NODES) ? cntI[i] : 0;
    sh[threadIdx.x] = v;
    __syncthreads();
    for (int s = 1; s < 256; s <<= 1) {
        int t = (threadIdx.x >= (unsigned)s) ? sh[threadIdx.x - s] : 0;
        __syncthreads();
        sh[threadIdx.x] += t;
        __syncthreads();
    }
    int excl = sh[threadIdx.x] - v + bsum[blockIdx.x];
    if (i < N_NODES) off[i] = excl;
    if (i == N_NODES - 1) off[N_NODES] = excl + v;
}

__global__ void k_scatter(const int* __restrict__ src, const int* __restrict__ dst,
                          const int* __restrict__ et, const int* __restrict__ off,
                          int* __restrict__ fill, unsigned int* __restrict__ se, int E) {
    int e = blockIdx.x * blockDim.x + threadIdx.x;
    if (e >= E) return;
    int d = dst[e];
    int pos = off[d] + atomicAdd(&fill[d], 1);
    se[pos] = (unsigned int)src[e] | ((unsigned int)et[e] << 17);
}

// ---- MFMA GEMM: [X @ Wb] -> Y8 (fp8 basis block, 256 B rows) + R (bf16 root, 64-col rows)
// ZT: zero the target node's output rows (layer 1 only; x[target]=0, output linear in x).
template<int KP, bool ZT>
__global__ __launch_bounds__(256) void k_gemm_mfma(const bf16* __restrict__ X,
                                                   const bf16* __restrict__ Wb,
                                                   unsigned char* __restrict__ Y8,
                                                   bf16* __restrict__ R, int M,
                                                   const int* __restrict__ tgt) {
    __shared__ bf16 smem[64 * 320];   // 40 KB
    int tid = threadIdx.x;
    int w = tid >> 6, lane = tid & 63;
    int quad = lane >> 4, cIn = lane & 15;
    int base_row = blockIdx.x * 64;

    const int TOT = 64 * KP / 8;
    for (int i = tid; i < TOT; i += 256) {
        int e8 = i * 8;
        int r = e8 / KP, c = e8 - r * KP;
        int row = base_row + r; if (row > M - 1) row = M - 1;
        *(uint4*)(&smem[r * KP + c]) = *(const uint4*)(&X[(size_t)row * KP + c]);
    }
    __syncthreads();

    f32x4 acc[20];
#pragma unroll
    for (int i = 0; i < 20; ++i) acc[i] = (f32x4){0.f, 0.f, 0.f, 0.f};

#pragma unroll
    for (int ks = 0; ks < KP / 32; ++ks) {
        short8 a = *(const short8*)(&smem[(w * 16 + cIn) * KP + ks * 32 + quad * 8]);
#pragma unroll
        for (int ct = 0; ct < 20; ++ct) {
            short8 b = *(const short8*)(&Wb[(size_t)((ks * 20 + ct) * 64 + lane) * 8]);
            acc[ct] = __builtin_amdgcn_mfma_f32_16x16x32_bf16(a, b, acc[ct], 0, 0, 0);
        }
    }
    __syncthreads();

#pragma unroll
    for (int ct = 0; ct < 20; ++ct)
#pragma unroll
        for (int r = 0; r < 4; ++r)
            smem[(w * 16 + quad * 4 + r) * 320 + ct * 16 + cIn] = f2b(acc[ct][r]);
    __syncthreads();

    int tv = -1;
    if (ZT) tv = tgt[0];
    int valid = M - base_row; if (valid > 64) valid = 64;

    // fp8 basis block: per row, cols 0..255 (250 real + 6 pad) as 64 uint32
    for (int i = tid; i < valid * 64; i += 256) {
        int r = i >> 6, cu = i & 63;
        int row = base_row + r;
        int c4 = cu * 4;
        unsigned p = pk4_f8(b2f(smem[r * 320 + c4 + 0]), b2f(smem[r * 320 + c4 + 1]),
                            b2f(smem[r * 320 + c4 + 2]), b2f(smem[r * 320 + c4 + 3]));
        if (ZT && row == tv) p = 0u;
        *(unsigned*)(Y8 + (size_t)row * 256 + c4) = p;
    }
    // root block: per row, 64 bf16 (50 real + 14 zero) as 32 uint32
    for (int i = tid; i < valid * 32; i += 256) {
        int r = i >> 5, cu = i & 31;
        int row = base_row + r;
        int j0 = cu * 2, j1 = j0 + 1;
        unsigned short ua = (j0 < 50) ? *(const unsigned short*)&smem[r * 320 + 250 + j0] : 0;
        unsigned short ub = (j1 < 50) ? *(const unsigned short*)&smem[r * 320 + 250 + j1] : 0;
        unsigned u = (unsigned)ua | ((unsigned)ub << 16);
        if (ZT && row == tv) u = 0u;
        *(unsigned*)((unsigned short*)R + (size_t)row * 64 + j0) = u;
    }
}

// ================= per-node gather-reduce (no atomics) =======================
#define EDGE_BODY(p, ACC)                                                     \
    {                                                                         \
        int s_ = __builtin_amdgcn_readfirstlane((int)((p) & 0x1FFFFu));       \
        int t_ = __builtin_amdgcn_readfirstlane((int)((p) >> 17));            \
        const unsigned char* yr_ = Y8 + (size_t)s_ * 256;                     \
        float a_ = b2f(rt[t_ * 50 + f]);                                      \
        _Pragma("unroll")                                                     \
        for (int b_ = 0; b_ < 5; ++b_)                                        \
            a_ += comp[t_ * 5 + b_] * f8tof(yr_[b_ * 50 + f]);                \
        ACC += a_;                                                            \
    }

#define REDUCE_LOOP                                                           \
    float acc = 0.f;                                                          \
    int e = e0;                                                               \
    for (; e + 8 <= e1; e += 8) {                                             \
        unsigned p0 = se[e],     p1 = se[e + 1], p2 = se[e + 2], p3 = se[e + 3]; \
        unsigned p4 = se[e + 4], p5 = se[e + 5], p6 = se[e + 6], p7 = se[e + 7]; \
        float a8 = 0.f;                                                       \
        EDGE_BODY(p0, a8) EDGE_BODY(p1, a8) EDGE_BODY(p2, a8) EDGE_BODY(p3, a8) \
        EDGE_BODY(p4, a8) EDGE_BODY(p5, a8) EDGE_BODY(p6, a8) EDGE_BODY(p7, a8) \
        acc += a8;                                                            \
    }                                                                         \
    for (; e < e1; ++e) {                                                     \
        unsigned p = se[e];                                                   \
        EDGE_BODY(p, acc)                                                     \
    }

// Layer 1: h[row][0..63] = mean_agg + x@root (R) + bias (cols>=50 zero)
__global__ __launch_bounds__(256) void k_reduce1(const int* __restrict__ off,
                                                 const unsigned int* __restrict__ se,
                                                 const float* __restrict__ comp,
                                                 const bf16* __restrict__ rt,
                                                 const unsigned char* __restrict__ Y8,
                                                 const bf16* __restrict__ R,
                                                 const float* __restrict__ bias_,
                                                 bf16* __restrict__ h) {
    int wid = threadIdx.x >> 6, lane = threadIdx.x & 63;
    int row = blockIdx.x * 4 + wid;
    if (row >= N_NODES) return;
    int e0 = off[row], e1 = off[row + 1];
    int f = (lane < 50) ? lane : 49;
    REDUCE_LOOP
    float c = (float)(e1 - e0); c = c > 1.f ? c : 1.f;
    float v = acc / c + b2f(R[(size_t)row * 64 + f]) + bias_[f];
    h[(size_t)row * 64 + lane] = f2b(lane < 50 ? v : 0.f);
}

// Layer 2: same reduce + log_softmax epilogue; dual-dtype output store.
__global__ __launch_bounds__(256) void k_reduce2(const int* __restrict__ off,
                                                 const unsigned int* __restrict__ se,
                                                 const float* __restrict__ comp,
                                                 const bf16* __restrict__ rt,
                                                 const unsigned char* __restrict__ Y8,
                                                 const bf16* __restrict__ R,
                                                 const float* __restrict__ bias_,
                                                 const int* __restrict__ flag,
                                                 void* __restrict__ out) {
    int wid = threadIdx.x >> 6, lane = threadIdx.x & 63;
    int row = blockIdx.x * 4 + wid;
    if (row >= N_NODES) return;
    int e0 = off[row], e1 = off[row + 1];
    int f = (lane < 50) ? lane : 49;
    REDUCE_LOOP
    float c = (float)(e1 - e0); c = c > 1.f ? c : 1.f;
    float v = -INFINITY;
    if (lane < 50)
        v = acc / c + b2f(R[(size_t)row * 64 + f]) + bias_[f];
    float m = v;
    for (int o = 32; o > 0; o >>= 1) m = fmaxf(m, __shfl_xor(m, o));
    float ex = (lane < 50) ? expf(v - m) : 0.f;
    float s = ex;
    for (int o = 32; o > 0; o >>= 1) s += __shfl_xor(s, o);
    float res = v - m - logf(s);
    if (lane < 50) {
        if (flag[0]) ((bf16*)out)[row * 50 + f] = f2b(res);
        else         ((float*)out)[row * 50 + f] = res;
    }
}

extern "C" void kernel_launch(void* const* d_in, const int* in_sizes, int n_in,
                              void* d_out, int out_size, void* d_ws, size_t ws_size,
                              hipStream_t stream) {
    const void* x_raw = d_in[0];
    const int*  ei    = (const int*)d_in[1];
    const int*  et    = (const int*)d_in[2];
    const int*  tgt   = (const int*)d_in[3];

    char* wsp = (char*)d_ws;
    size_t off_b = 0;
    auto alloc = [&](size_t bytes) {
        void* p = wsp + off_b;
        off_b = (off_b + bytes + 255) & ~(size_t)255;
        return p;
    };
    unsigned char* Y8 = (unsigned char*)alloc((size_t)N_NODES * 256);       // 25.6 MB fp8 basis
    bf16*  R    = (bf16*) alloc((size_t)N_NODES * 64 * sizeof(bf16));       // 12.8 MB bf16 root
    bf16*  xc   = (bf16*) alloc((size_t)N_NODES * 128 * sizeof(bf16));      // 25.6 MB
    bf16*  h    = xc;   // alias: xc dead after layer-1 GEMM; h is [N_NODES][64]
    unsigned int* se = (unsigned int*)alloc((size_t)N_EDGES * sizeof(unsigned int));
    int*   cntI = (int*)  alloc((size_t)N_NODES * sizeof(int));
    int*   offs = (int*)  alloc((size_t)(N_NODES + 1) * sizeof(int));
    int*   fill = (int*)  alloc((size_t)N_NODES * sizeof(int));
    int*   bsum = (int*)  alloc((size_t)NBLK * sizeof(int));
    float* wc   = (float*)alloc((size_t)W_TOTAL * sizeof(float));
    bf16*  Wb1  = (bf16*) alloc((size_t)40960 * sizeof(bf16));   // 4 ksteps x 10240
    bf16*  Wb2  = (bf16*) alloc((size_t)20480 * sizeof(bf16));   // 2 ksteps x 10240
    bf16*  rt1  = (bf16*) alloc((size_t)N_REL2 * 50 * sizeof(bf16));
    bf16*  rt2  = (bf16*) alloc((size_t)N_REL2 * 50 * sizeof(bf16));
    int*   flag = (int*)  alloc(sizeof(int));

    const int* srcp = ei;
    const int* dstp = ei + N_EDGES;

    hipMemsetAsync(cntI, 0, (size_t)N_NODES * sizeof(int), stream);
    hipMemsetAsync(fill, 0, (size_t)N_NODES * sizeof(int), stream);

    WPtrs wp;
    for (int i = 0; i < 10; ++i) wp.p[i] = d_in[4 + i];

    k_detect<<<1, 256, 0, stream>>>((const unsigned short*)x_raw, flag);
    k_prep1<<<P1_TOTAL, 256, 0, stream>>>(x_raw, flag, xc, wp, wc, dstp, cntI);
    k_prep2<<<P2_TOTAL, 256, 0, stream>>>(wc, Wb1, Wb2, rt1, rt2, cntI, bsum);
    k_s2<<<1, 64, 0, stream>>>(bsum);
    k_s3<<<NBLK, 256, 0, stream>>>(cntI, bsum, offs);
    k_scatter<<<(N_EDGES + 255) / 256, 256, 0, stream>>>(srcp, dstp, et, offs, fill, se, N_EDGES);

    // Layer 1
    k_gemm_mfma<128, true><<<(N_NODES + 63) / 64, 256, 0, stream>>>(xc, Wb1, Y8, R, N_NODES, tgt);
    k_reduce1<<<(N_NODES + 3) / 4, 256, 0, stream>>>(offs, se, wc + O_COMP1, rt1, Y8, R, wc + O_BIAS1, h);

    // Layer 2 (Y8/R reused; stream-ordered so reduce1 reads finish first)
    k_gemm_mfma<64, false><<<(N_NODES + 63) / 64, 256, 0, stream>>>(h, Wb2, Y8, R, N_NODES, nullptr);
    k_reduce2<<<(N_NODES + 3) / 4, 256, 0, stream>>>(offs, se, wc + O_COMP2, rt2, Y8, R, wc + O_BIAS2, flag, d_out);
}

// Round 7
// 581.731 us; speedup vs baseline: 4.5457x; 1.0224x over previous
//
#include <hip/hip_runtime.h>
#include <hip/hip_bf16.h>

typedef __hip_bfloat16 bf16;

#define N_NODES 100000
#define N_EDGES 1600000
#define D_IN    100
#define D_HID   50
#define N_REL   237
#define N_REL2  474
#define N_CLASS 50
#define NBLK    391   // ceil(N_NODES/256)

// Canonical fp32 weight-block offsets (element offsets into wc)
#define O_RELEMB 0
#define O_RELW   23700
#define O_BASIS1 28700
#define O_COMP1  53700
#define O_ROOT1  56070
#define O_BIAS1  61070
#define O_BASIS2 61120
#define O_COMP2  73620
#define O_ROOT2  75990
#define O_BIAS2  78490
#define W_TOTAL  78540

// prep1 grid partition (256-thread blocks)
#define P1_CVTX_BLKS 50000            // N_NODES*128/256
#define P1_CVTW_BLKS 307              // ceil(W_TOTAL/256)
#define P1_HIST_BLKS 6250             // N_EDGES/256
#define P1_TOTAL (P1_CVTX_BLKS + P1_CVTW_BLKS + P1_HIST_BLKS)

// prep2 grid partition
#define P2_PACK1_BLKS 160             // 4 ksteps * 10240 / 256
#define P2_PACK2_BLKS 80
#define P2_REL_BLKS   474
#define P2_S1_BLKS    NBLK
#define P2_TOTAL (P2_PACK1_BLKS + P2_PACK2_BLKS + P2_REL_BLKS + P2_S1_BLKS)

typedef __attribute__((ext_vector_type(8))) short short8;
typedef __attribute__((ext_vector_type(4))) float f32x4;

__device__ __forceinline__ float b2f(bf16 v) { return __bfloat162float(v); }
__device__ __forceinline__ bf16  f2b(float v) { return __float2bfloat16(v); }

#if __has_builtin(__builtin_amdgcn_cvt_f32_fp8) && __has_builtin(__builtin_amdgcn_cvt_pk_fp8_f32)
#define F8_HW 1
#endif

// ---- fp8 e4m3 (OCP, gfx950 HW) helpers ----
__device__ __forceinline__ float f8tof(unsigned u) {
#ifdef F8_HW
    return __builtin_amdgcn_cvt_f32_fp8((int)u, 0);
#else
    unsigned s = u >> 7, e = (u >> 3) & 0xF, m = u & 7;
    float v;
    if (e == 0) v = (float)m * 0.001953125f;                       // m * 2^-9
    else        v = (float)(8 + m) * __builtin_ldexpf(1.f, (int)e - 10);
    return s ? -v : v;
#endif
}

#ifdef F8_HW
#define F8SEL(u, s) __builtin_amdgcn_cvt_f32_fp8((int)(u), (s))
#else
#define F8SEL(u, s) f8tof(((u) >> (8 * (s))) & 0xFFu)
#endif

__device__ __forceinline__ unsigned f8enc_sw(float v) {
    unsigned bits = __float_as_uint(v);
    unsigned s = bits >> 31;
    float a = fabsf(v);
    if (a < 0.0009765625f) return s << 7;
    if (a >= 448.f) return (s << 7) | 0x7E;
    int E = (int)((bits >> 23) & 0xFF) - 127;
    unsigned m = bits & 0x7FFFFF;
    if (E < -6) {
        int q = (int)rintf(a * 512.f);
        if (q > 7) q = 7;
        return (s << 7) | (unsigned)q;
    }
    unsigned lsb = (m >> 20) & 1, rnd = (m >> 19) & 1;
    unsigned sticky = (m & 0x7FFFF) ? 1u : 0u;
    unsigned m3 = (m >> 20) + (rnd & (sticky | lsb));
    if (m3 == 8) { m3 = 0; E += 1; }
    if (E > 8) return (s << 7) | 0x7E;
    return (s << 7) | ((unsigned)(E + 7) << 3) | m3;
}

__device__ __forceinline__ unsigned pk4_f8(float v0, float v1, float v2, float v3) {
#ifdef F8_HW
    int p = __builtin_amdgcn_cvt_pk_fp8_f32(v0, v1, 0, false);
    p = __builtin_amdgcn_cvt_pk_fp8_f32(v2, v3, p, true);
    return (unsigned)p;
#else
    return f8enc_sw(v0) | (f8enc_sw(v1) << 8) | (f8enc_sw(v2) << 16) | (f8enc_sw(v3) << 24);
#endif
}

// ---- dtype detection: flag[0]=1 if float arrays are stored as bf16, 0 if fp32.
__global__ void k_detect(const unsigned short* __restrict__ xr, int* __restrict__ flag) {
    int tid = threadIdx.x;
    int cnt = 0;
    for (int i = tid; i < 4096; i += 256) {
        unsigned short u = xr[2 * i];
        unsigned e = (u >> 7) & 0xFF;
        bool pl = (e >= 107 && e <= 132) || ((u & 0x7FFF) == 0);
        cnt += pl ? 1 : 0;
    }
    __shared__ int sh[256];
    sh[tid] = cnt;
    __syncthreads();
    for (int s = 128; s > 0; s >>= 1) {
        if (tid < s) sh[tid] += sh[tid + s];
        __syncthreads();
    }
    if (tid == 0) flag[0] = (sh[0] >= 3072) ? 1 : 0;
}

struct WPtrs { const void* p[10]; };

// ================= fused prep1: convert_x | convert_w | hist =================
__global__ __launch_bounds__(256) void k_prep1(const void* __restrict__ xr,
                                               const int* __restrict__ flag,
                                               bf16* __restrict__ xc,
                                               WPtrs wp, float* __restrict__ wc,
                                               const int* __restrict__ dstp,
                                               int* __restrict__ cntI) {
    int blk = blockIdx.x;
    if (blk < P1_CVTX_BLKS) {
        int g = blk * 256 + threadIdx.x;
        int row = g >> 7, col = g & 127;
        bf16 o = f2b(0.f);
        if (col < D_IN) {
            if (flag[0]) o = ((const bf16*)xr)[row * D_IN + col];
            else         o = f2b(((const float*)xr)[row * D_IN + col]);
        }
        xc[g] = o;
        return;
    }
    blk -= P1_CVTX_BLKS;
    if (blk < P1_CVTW_BLKS) {
        const int sz[10] = {23700, 5000, 25000, 2370, 5000, 50, 12500, 2370, 2500, 50};
        int g = blk * 256 + threadIdx.x;
        if (g >= W_TOTAL) return;
        int j = 0, base = 0;
        while (j < 9 && g >= base + sz[j]) { base += sz[j]; ++j; }
        int idx = g - base;
        float v;
        if (flag[0]) v = b2f(((const bf16*)wp.p[j])[idx]);
        else         v = ((const float*)wp.p[j])[idx];
        wc[g] = v;
        return;
    }
    blk -= P1_CVTW_BLKS;
    {
        int e = blk * 256 + threadIdx.x;
        if (e < N_EDGES) atomicAdd(&cntI[dstp[e]], 1);
    }
}

// ---- pack job body: basis[5][KL][50] + root[KL][50] -> MFMA B-fragment order
__device__ __forceinline__ void job_pack(int blk, const float* basis, const float* root,
                                         bf16* Wb, int KL) {
    int g = blk * 256 + threadIdx.x;
    int ks = g / 10240;
    int r = g - ks * 10240;
    int ct = r >> 9;
    int r2 = r & 511;
    int l = r2 >> 3, j = r2 & 7;
    int k = ks * 32 + ((l >> 4) << 3) + j;
    int n = ct * 16 + (l & 15);
    float v = 0.f;
    if (k < KL && n < 300) {
        if (n < 250) { int b = n / 50, f = n - b * 50; v = basis[(b * KL + k) * 50 + f]; }
        else         v = root[k * 50 + (n - 250)];
    }
    Wb[g] = f2b(v);
}

// ================= fused prep2: pack1 | pack2 | rel | s1 =====================
__global__ __launch_bounds__(256) void k_prep2(const float* __restrict__ wc,
                                               bf16* __restrict__ Wb1, bf16* __restrict__ Wb2,
                                               bf16* __restrict__ rt1, bf16* __restrict__ rt2,
                                               const int* __restrict__ cntI,
                                               int* __restrict__ bsum) {
    int blk = blockIdx.x;
    if (blk < P2_PACK1_BLKS) { job_pack(blk, wc + O_BASIS1, wc + O_ROOT1, Wb1, D_IN); return; }
    blk -= P2_PACK1_BLKS;
    if (blk < P2_PACK2_BLKS) { job_pack(blk, wc + O_BASIS2, wc + O_ROOT2, Wb2, D_HID); return; }
    blk -= P2_PACK2_BLKS;
    if (blk < P2_REL_BLKS) {
        const float* rel_emb = wc + O_RELEMB;
        const float* rel_w   = wc + O_RELW;
        const float* basis1  = wc + O_BASIS1;
        const float* comp1   = wc + O_COMP1;
        const float* basis2  = wc + O_BASIS2;
        const float* comp2   = wc + O_COMP2;
        int t = blk;
        int tid = threadIdx.x;
        __shared__ float rf[D_IN];
        __shared__ float r2s[D_HID];
        int tm = (t >= N_REL) ? t - N_REL : t;
        if (tid < D_IN) rf[tid] = rel_emb[tm * D_IN + tid];
        __syncthreads();
        if (tid < 50) {
            int f = tid;
            float a = 0.f;
            for (int b = 0; b < 5; ++b) {
                float cb = comp1[t * 5 + b];
                float s = 0.f;
                for (int k = 0; k < D_IN; ++k) s += rf[k] * basis1[(b * D_IN + k) * 50 + f];
                a += cb * s;
            }
            rt1[t * 50 + f] = f2b(a);
            float s2 = 0.f;
            for (int k = 0; k < D_IN; ++k) s2 += rf[k] * rel_w[k * 50 + f];
            r2s[f] = s2;
        }
        __syncthreads();
        if (tid < 50) {
            int f = tid;
            float a = 0.f;
            for (int b = 0; b < 5; ++b) {
                float cb = comp2[t * 5 + b];
                float s = 0.f;
                for (int k = 0; k < 50; ++k) s += r2s[k] * basis2[(b * 50 + k) * 50 + f];
                a += cb * s;
            }
            rt2[t * 50 + f] = f2b(a);
        }
        return;
    }
    blk -= P2_REL_BLKS;
    {
        __shared__ int sh[256];
        int i = blk * 256 + threadIdx.x;
        sh[threadIdx.x] = (i < N_NODES) ? cntI[i] : 0;
        __syncthreads();
        for (int s = 128; s > 0; s >>= 1) {
            if (threadIdx.x < s) sh[threadIdx.x] += sh[threadIdx.x + s];
            __syncthreads();
        }
        if (threadIdx.x == 0) bsum[blk] = sh[0];
    }
}

// single-wave shuffle exclusive scan over NBLK block sums
__global__ void k_s2(int* __restrict__ bsum) {
    int lane = threadIdx.x;   // 64
    int carry = 0;
    for (int c = 0; c < (NBLK + 63) / 64; ++c) {
        int idx = c * 64 + lane;
        int v = (idx < NBLK) ? bsum[idx] : 0;
        int orig = v;
        for (int o = 1; o < 64; o <<= 1) {
            int t = __shfl_up(v, o);
            if (lane >= o) v += t;
        }
        if (idx < NBLK) bsum[idx] = carry + v - orig;
        carry += __shfl(v, 63);
    }
}

__global__ void k_s3(const int* __restrict__ cntI, const int* __restrict__ bsum,
                     int* __restrict__ off) {
    __shared__ int sh[256];
    int i = blockIdx.x * 256 + threadIdx.x;
    int v = (i < N_NODES) ? cntI[i] : 0;
    sh[threadIdx.x] = v;
    __syncthreads();
    for (int s = 1; s < 256; s <<= 1) {
        int t = (threadIdx.x >= (unsigned)s) ? sh[threadIdx.x - s] : 0;
        __syncthreads();
        sh[threadIdx.x] += t;
        __syncthreads();
    }
    int excl = sh[threadIdx.x] - v + bsum[blockIdx.x];
    if (i < N_NODES) off[i] = excl;
    if (i == N_NODES - 1) off[N_NODES] = excl + v;
}

__global__ void k_scatter(const int* __restrict__ src, const int* __restrict__ dst,
                          const int* __restrict__ et, const int* __restrict__ off,
                          int* __restrict__ fill, unsigned int* __restrict__ se, int E) {
    int e = blockIdx.x * blockDim.x + threadIdx.x;
    if (e >= E) return;
    int d = dst[e];
    int pos = off[d] + atomicAdd(&fill[d], 1);
    se[pos] = (unsigned int)src[e] | ((unsigned int)et[e] << 17);
}

// ---- MFMA GEMM: [X @ Wb] -> Y8 (fp8, plane-split 256 B rows) + R (bf16 root)
// Y8 row layout: bytes [0,200): dword f (f=0..49) = fp8 of basis cols {f,50+f,100+f,150+f};
//                bytes [200,250): byte f = fp8 of basis col 200+f (b=4); [250,256) pad.
// ZT: zero the target node's output rows (layer 1 only; x[target]=0, output linear in x).
template<int KP, bool ZT>
__global__ __launch_bounds__(256) void k_gemm_mfma(const bf16* __restrict__ X,
                                                   const bf16* __restrict__ Wb,
                                                   unsigned char* __restrict__ Y8,
                                                   bf16* __restrict__ R, int M,
                                                   const int* __restrict__ tgt) {
    __shared__ bf16 smem[64 * 320];   // 40 KB
    int tid = threadIdx.x;
    int w = tid >> 6, lane = tid & 63;
    int quad = lane >> 4, cIn = lane & 15;
    int base_row = blockIdx.x * 64;

    const int TOT = 64 * KP / 8;
    for (int i = tid; i < TOT; i += 256) {
        int e8 = i * 8;
        int r = e8 / KP, c = e8 - r * KP;
        int row = base_row + r; if (row > M - 1) row = M - 1;
        *(uint4*)(&smem[r * KP + c]) = *(const uint4*)(&X[(size_t)row * KP + c]);
    }
    __syncthreads();

    f32x4 acc[20];
#pragma unroll
    for (int i = 0; i < 20; ++i) acc[i] = (f32x4){0.f, 0.f, 0.f, 0.f};

#pragma unroll
    for (int ks = 0; ks < KP / 32; ++ks) {
        short8 a = *(const short8*)(&smem[(w * 16 + cIn) * KP + ks * 32 + quad * 8]);
#pragma unroll
        for (int ct = 0; ct < 20; ++ct) {
            short8 b = *(const short8*)(&Wb[(size_t)((ks * 20 + ct) * 64 + lane) * 8]);
            acc[ct] = __builtin_amdgcn_mfma_f32_16x16x32_bf16(a, b, acc[ct], 0, 0, 0);
        }
    }
    __syncthreads();

#pragma unroll
    for (int ct = 0; ct < 20; ++ct)
#pragma unroll
        for (int r = 0; r < 4; ++r)
            smem[(w * 16 + quad * 4 + r) * 320 + ct * 16 + cIn] = f2b(acc[ct][r]);
    __syncthreads();

    int tv = -1;
    if (ZT) tv = tgt[0];
    int valid = M - base_row; if (valid > 64) valid = 64;

    // plane-split fp8 basis block: per row, 64 dwords
    for (int i = tid; i < valid * 64; i += 256) {
        int r = i >> 6, u = i & 63;
        int row = base_row + r;
        unsigned pbits;
        if (u < 50) {
            pbits = pk4_f8(b2f(smem[r * 320 + u]),       b2f(smem[r * 320 + 50 + u]),
                           b2f(smem[r * 320 + 100 + u]), b2f(smem[r * 320 + 150 + u]));
        } else if (u < 63) {
            int fb = (u - 50) * 4;
            float v0 = (fb + 0 < 50) ? b2f(smem[r * 320 + 200 + fb + 0]) : 0.f;
            float v1 = (fb + 1 < 50) ? b2f(smem[r * 320 + 200 + fb + 1]) : 0.f;
            float v2 = (fb + 2 < 50) ? b2f(smem[r * 320 + 200 + fb + 2]) : 0.f;
            float v3 = (fb + 3 < 50) ? b2f(smem[r * 320 + 200 + fb + 3]) : 0.f;
            pbits = pk4_f8(v0, v1, v2, v3);
        } else {
            pbits = 0u;
        }
        if (ZT && row == tv) pbits = 0u;
        *(unsigned*)(Y8 + (size_t)row * 256 + u * 4) = pbits;
    }
    // root block: per row, 64 bf16 (50 real + 14 zero) as 32 uint32
    for (int i = tid; i < valid * 32; i += 256) {
        int r = i >> 5, cu = i & 31;
        int row = base_row + r;
        int j0 = cu * 2, j1 = j0 + 1;
        unsigned short ua = (j0 < 50) ? *(const unsigned short*)&smem[r * 320 + 250 + j0] : 0;
        unsigned short ub = (j1 < 50) ? *(const unsigned short*)&smem[r * 320 + 250 + j1] : 0;
        unsigned u = (unsigned)ua | ((unsigned)ub << 16);
        if (ZT && row == tv) u = 0u;
        *(unsigned*)((unsigned short*)R + (size_t)row * 64 + j0) = u;
    }
}

// ================= per-node gather-reduce (no atomics) =======================
// Per edge per lane: 1 aligned dword (b=0..3 via cvt byte-select) + 1 byte (b=4) + 1 rt load.
#define EDGE_BODY(p, ACC)                                                     \
    {                                                                         \
        int s_ = __builtin_amdgcn_readfirstlane((int)((p) & 0x1FFFFu));       \
        int t_ = __builtin_amdgcn_readfirstlane((int)((p) >> 17));            \
        const unsigned char* yr_ = Y8 + (size_t)s_ * 256;                     \
        unsigned a4_ = *(const unsigned*)(yr_ + 4 * f);                       \
        float b4_ = f8tof(yr_[200 + f]);                                      \
        float a_ = b2f(rt[t_ * 50 + f]);                                      \
        a_ += comp[t_ * 5 + 0] * F8SEL(a4_, 0);                               \
        a_ += comp[t_ * 5 + 1] * F8SEL(a4_, 1);                               \
        a_ += comp[t_ * 5 + 2] * F8SEL(a4_, 2);                               \
        a_ += comp[t_ * 5 + 3] * F8SEL(a4_, 3);                               \
        a_ += comp[t_ * 5 + 4] * b4_;                                         \
        ACC += a_;                                                            \
    }

#define REDUCE_LOOP                                                           \
    float acc = 0.f;                                                          \
    int e = e0;                                                               \
    for (; e + 8 <= e1; e += 8) {                                             \
        unsigned p0 = se[e],     p1 = se[e + 1], p2 = se[e + 2], p3 = se[e + 3]; \
        unsigned p4 = se[e + 4], p5 = se[e + 5], p6 = se[e + 6], p7 = se[e + 7]; \
        float a8 = 0.f;                                                       \
        EDGE_BODY(p0, a8) EDGE_BODY(p1, a8) EDGE_BODY(p2, a8) EDGE_BODY(p3, a8) \
        EDGE_BODY(p4, a8) EDGE_BODY(p5, a8) EDGE_BODY(p6, a8) EDGE_BODY(p7, a8) \
        acc += a8;                                                            \
    }                                                                         \
    for (; e < e1; ++e) {                                                     \
        unsigned p = se[e];                                                   \
        EDGE_BODY(p, acc)                                                     \
    }

// Layer 1: h[row][0..63] = mean_agg + x@root (R) + bias (cols>=50 zero)
__global__ __launch_bounds__(256) void k_reduce1(const int* __restrict__ off,
                                                 const unsigned int* __restrict__ se,
                                                 const float* __restrict__ comp,
                                                 const bf16* __restrict__ rt,
                                                 const unsigned char* __restrict__ Y8,
                                                 const bf16* __restrict__ R,
                                                 const float* __restrict__ bias_,
                                                 bf16* __restrict__ h) {
    int wid = threadIdx.x >> 6, lane = threadIdx.x & 63;
    int row = blockIdx.x * 4 + wid;
    if (row >= N_NODES) return;
    int e0 = off[row], e1 = off[row + 1];
    int f = (lane < 50) ? lane : 49;
    REDUCE_LOOP
    float c = (float)(e1 - e0); c = c > 1.f ? c : 1.f;
    float v = acc / c + b2f(R[(size_t)row * 64 + f]) + bias_[f];
    h[(size_t)row * 64 + lane] = f2b(lane < 50 ? v : 0.f);
}

// Layer 2: same reduce + log_softmax epilogue; dual-dtype output store.
__global__ __launch_bounds__(256) void k_reduce2(const int* __restrict__ off,
                                                 const unsigned int* __restrict__ se,
                                                 const float* __restrict__ comp,
                                                 const bf16* __restrict__ rt,
                                                 const unsigned char* __restrict__ Y8,
                                                 const bf16* __restrict__ R,
                                                 const float* __restrict__ bias_,
                                                 const int* __restrict__ flag,
                                                 void* __restrict__ out) {
    int wid = threadIdx.x >> 6, lane = threadIdx.x & 63;
    int row = blockIdx.x * 4 + wid;
    if (row >= N_NODES) return;
    int e0 = off[row], e1 = off[row + 1];
    int f = (lane < 50) ? lane : 49;
    REDUCE_LOOP
    float c = (float)(e1 - e0); c = c > 1.f ? c : 1.f;
    float v = -INFINITY;
    if (lane < 50)
        v = acc / c + b2f(R[(size_t)row * 64 + f]) + bias_[f];
    float m = v;
    for (int o = 32; o > 0; o >>= 1) m = fmaxf(m, __shfl_xor(m, o));
    float ex = (lane < 50) ? expf(v - m) : 0.f;
    float s = ex;
    for (int o = 32; o > 0; o >>= 1) s += __shfl_xor(s, o);
    float res = v - m - logf(s);
    if (lane < 50) {
        if (flag[0]) ((bf16*)out)[row * 50 + f] = f2b(res);
        else         ((float*)out)[row * 50 + f] = res;
    }
}

extern "C" void kernel_launch(void* const* d_in, const int* in_sizes, int n_in,
                              void* d_out, int out_size, void* d_ws, size_t ws_size,
                              hipStream_t stream) {
    const void* x_raw = d_in[0];
    const int*  ei    = (const int*)d_in[1];
    const int*  et    = (const int*)d_in[2];
    const int*  tgt   = (const int*)d_in[3];

    char* wsp = (char*)d_ws;
    size_t off_b = 0;
    auto alloc = [&](size_t bytes) {
        void* p = wsp + off_b;
        off_b = (off_b + bytes + 255) & ~(size_t)255;
        return p;
    };
    unsigned char* Y8 = (unsigned char*)alloc((size_t)N_NODES * 256);       // 25.6 MB fp8 basis
    bf16*  R    = (bf16*) alloc((size_t)N_NODES * 64 * sizeof(bf16));       // 12.8 MB bf16 root
    bf16*  xc   = (bf16*) alloc((size_t)N_NODES * 128 * sizeof(bf16));      // 25.6 MB
    bf16*  h    = xc;   // alias: xc dead after layer-1 GEMM; h is [N_NODES][64]
    unsigned int* se = (unsigned int*)alloc((size_t)N_EDGES * sizeof(unsigned int));
    int*   cntI = (int*)  alloc((size_t)N_NODES * sizeof(int));
    int*   offs = (int*)  alloc((size_t)(N_NODES + 1) * sizeof(int));
    int*   fill = (int*)  alloc((size_t)N_NODES * sizeof(int));
    int*   bsum = (int*)  alloc((size_t)NBLK * sizeof(int));
    float* wc   = (float*)alloc((size_t)W_TOTAL * sizeof(float));
    bf16*  Wb1  = (bf16*) alloc((size_t)40960 * sizeof(bf16));   // 4 ksteps x 10240
    bf16*  Wb2  = (bf16*) alloc((size_t)20480 * sizeof(bf16));   // 2 ksteps x 10240
    bf16*  rt1  = (bf16*) alloc((size_t)N_REL2 * 50 * sizeof(bf16));
    bf16*  rt2  = (bf16*) alloc((size_t)N_REL2 * 50 * sizeof(bf16));
    int*   flag = (int*)  alloc(sizeof(int));

    const int* srcp = ei;
    const int* dstp = ei + N_EDGES;

    hipMemsetAsync(cntI, 0, (size_t)N_NODES * sizeof(int), stream);
    hipMemsetAsync(fill, 0, (size_t)N_NODES * sizeof(int), stream);

    WPtrs wp;
    for (int i = 0; i < 10; ++i) wp.p[i] = d_in[4 + i];

    k_detect<<<1, 256, 0, stream>>>((const unsigned short*)x_raw, flag);
    k_prep1<<<P1_TOTAL, 256, 0, stream>>>(x_raw, flag, xc, wp, wc, dstp, cntI);
    k_prep2<<<P2_TOTAL, 256, 0, stream>>>(wc, Wb1, Wb2, rt1, rt2, cntI, bsum);
    k_s2<<<1, 64, 0, stream>>>(bsum);
    k_s3<<<NBLK, 256, 0, stream>>>(cntI, bsum, offs);
    k_scatter<<<(N_EDGES + 255) / 256, 256, 0, stream>>>(srcp, dstp, et, offs, fill, se, N_EDGES);

    // Layer 1
    k_gemm_mfma<128, true><<<(N_NODES + 63) / 64, 256, 0, stream>>>(xc, Wb1, Y8, R, N_NODES, tgt);
    k_reduce1<<<(N_NODES + 3) / 4, 256, 0, stream>>>(offs, se, wc + O_COMP1, rt1, Y8, R, wc + O_BIAS1, h);

    // Layer 2 (Y8/R reused; stream-ordered so reduce1 reads finish first)
    k_gemm_mfma<64, false><<<(N_NODES + 63) / 64, 256, 0, stream>>>(h, Wb2, Y8, R, N_NODES, nullptr);
    k_reduce2<<<(N_NODES + 3) / 4, 256, 0, stream>>>(offs, se, wc + O_COMP2, rt2, Y8, R, wc + O_BIAS2, flag, d_out);
}

// Round 8
// 578.970 us; speedup vs baseline: 4.5674x; 1.0048x over previous
//
#include <hip/hip_runtime.h>
#include <hip/hip_bf16.h>

typedef __hip_bfloat16 bf16;

#define N_NODES 100000
#define N_EDGES 1600000
#define D_IN    100
#define D_HID   50
#define N_REL   237
#define N_REL2  474
#define N_CLASS 50
#define NBLK    391   // ceil(N_NODES/256)

// Canonical fp32 weight-block offsets (element offsets into wc)
#define O_RELEMB 0
#define O_RELW   23700
#define O_BASIS1 28700
#define O_COMP1  53700
#define O_ROOT1  56070
#define O_BIAS1  61070
#define O_BASIS2 61120
#define O_COMP2  73620
#define O_ROOT2  75990
#define O_BIAS2  78490
#define W_TOTAL  78540

// prep1 grid partition (256-thread blocks)
#define P1_CVTX_BLKS 50000            // N_NODES*128/256
#define P1_CVTW_BLKS 307              // ceil(W_TOTAL/256)
#define P1_HIST_BLKS 6250             // N_EDGES/256
#define P1_TOTAL (P1_CVTX_BLKS + P1_CVTW_BLKS + P1_HIST_BLKS)

// prep2 grid partition
#define P2_PACK1_BLKS 160             // 4 ksteps * 10240 / 256
#define P2_PACK2_BLKS 80
#define P2_REL_BLKS   474
#define P2_S1_BLKS    NBLK
#define P2_TOTAL (P2_PACK1_BLKS + P2_PACK2_BLKS + P2_REL_BLKS + P2_S1_BLKS)

// binned scatter
#define NBUCK    128
#define BSHIFT   10
#define BCAP     20480                // >> max bucket size (~16.4K +- 127)
#define BIN_EPB  1024
#define BIN_BLKS ((N_EDGES + BIN_EPB - 1) / BIN_EPB)
#define S2_JPB   20                   // BCAP / BIN_EPB blocks per bucket

typedef __attribute__((ext_vector_type(8))) short short8;
typedef __attribute__((ext_vector_type(4))) float f32x4;
typedef __attribute__((ext_vector_type(2))) float f32x2;

__device__ __forceinline__ float b2f(bf16 v) { return __bfloat162float(v); }
__device__ __forceinline__ bf16  f2b(float v) { return __float2bfloat16(v); }

#if __has_builtin(__builtin_amdgcn_cvt_f32_fp8) && __has_builtin(__builtin_amdgcn_cvt_pk_fp8_f32)
#define F8_HW 1
#endif
#if __has_builtin(__builtin_amdgcn_cvt_pk_f32_fp8)
#define F8PK_HW 1
#endif

// ---- fp8 e4m3 (OCP, gfx950 HW) helpers ----
__device__ __forceinline__ float f8tof(unsigned u) {
#ifdef F8_HW
    return __builtin_amdgcn_cvt_f32_fp8((int)u, 0);
#else
    unsigned s = u >> 7, e = (u >> 3) & 0xF, m = u & 7;
    float v;
    if (e == 0) v = (float)m * 0.001953125f;
    else        v = (float)(8 + m) * __builtin_ldexpf(1.f, (int)e - 10);
    return s ? -v : v;
#endif
}

#ifdef F8_HW
#define F8SEL(u, s) __builtin_amdgcn_cvt_f32_fp8((int)(u), (s))
#else
#define F8SEL(u, s) f8tof(((u) >> (8 * (s))) & 0xFFu)
#endif

template <bool HI>
__device__ __forceinline__ f32x2 f8pk(unsigned u) {
#ifdef F8PK_HW
    return __builtin_amdgcn_cvt_pk_f32_fp8((int)u, HI);
#else
    f32x2 r;
    r.x = F8SEL(u, HI ? 2 : 0);
    r.y = F8SEL(u, HI ? 3 : 1);
    return r;
#endif
}

__device__ __forceinline__ unsigned f8enc_sw(float v) {
    unsigned bits = __float_as_uint(v);
    unsigned s = bits >> 31;
    float a = fabsf(v);
    if (a < 0.0009765625f) return s << 7;
    if (a >= 448.f) return (s << 7) | 0x7E;
    int E = (int)((bits >> 23) & 0xFF) - 127;
    unsigned m = bits & 0x7FFFFF;
    if (E < -6) {
        int q = (int)rintf(a * 512.f);
        if (q > 7) q = 7;
        return (s << 7) | (unsigned)q;
    }
    unsigned lsb = (m >> 20) & 1, rnd = (m >> 19) & 1;
    unsigned sticky = (m & 0x7FFFF) ? 1u : 0u;
    unsigned m3 = (m >> 20) + (rnd & (sticky | lsb));
    if (m3 == 8) { m3 = 0; E += 1; }
    if (E > 8) return (s << 7) | 0x7E;
    return (s << 7) | ((unsigned)(E + 7) << 3) | m3;
}

__device__ __forceinline__ unsigned pk4_f8(float v0, float v1, float v2, float v3) {
#ifdef F8_HW
    int p = __builtin_amdgcn_cvt_pk_fp8_f32(v0, v1, 0, false);
    p = __builtin_amdgcn_cvt_pk_fp8_f32(v2, v3, p, true);
    return (unsigned)p;
#else
    return f8enc_sw(v0) | (f8enc_sw(v1) << 8) | (f8enc_sw(v2) << 16) | (f8enc_sw(v3) << 24);
#endif
}

// ---- dtype detection: flag[0]=1 if float arrays are stored as bf16, 0 if fp32.
__global__ void k_detect(const unsigned short* __restrict__ xr, int* __restrict__ flag) {
    int tid = threadIdx.x;
    int cnt = 0;
    for (int i = tid; i < 4096; i += 256) {
        unsigned short u = xr[2 * i];
        unsigned e = (u >> 7) & 0xFF;
        bool pl = (e >= 107 && e <= 132) || ((u & 0x7FFF) == 0);
        cnt += pl ? 1 : 0;
    }
    __shared__ int sh[256];
    sh[tid] = cnt;
    __syncthreads();
    for (int s = 128; s > 0; s >>= 1) {
        if (tid < s) sh[tid] += sh[tid + s];
        __syncthreads();
    }
    if (tid == 0) flag[0] = (sh[0] >= 3072) ? 1 : 0;
}

struct WPtrs { const void* p[10]; };

// ================= fused prep1: convert_x | convert_w | hist =================
__global__ __launch_bounds__(256) void k_prep1(const void* __restrict__ xr,
                                               const int* __restrict__ flag,
                                               bf16* __restrict__ xc,
                                               WPtrs wp, float* __restrict__ wc,
                                               const int* __restrict__ dstp,
                                               int* __restrict__ cntI) {
    int blk = blockIdx.x;
    if (blk < P1_CVTX_BLKS) {
        int g = blk * 256 + threadIdx.x;
        int row = g >> 7, col = g & 127;
        bf16 o = f2b(0.f);
        if (col < D_IN) {
            if (flag[0]) o = ((const bf16*)xr)[row * D_IN + col];
            else         o = f2b(((const float*)xr)[row * D_IN + col]);
        }
        xc[g] = o;
        return;
    }
    blk -= P1_CVTX_BLKS;
    if (blk < P1_CVTW_BLKS) {
        const int sz[10] = {23700, 5000, 25000, 2370, 5000, 50, 12500, 2370, 2500, 50};
        int g = blk * 256 + threadIdx.x;
        if (g >= W_TOTAL) return;
        int j = 0, base = 0;
        while (j < 9 && g >= base + sz[j]) { base += sz[j]; ++j; }
        int idx = g - base;
        float v;
        if (flag[0]) v = b2f(((const bf16*)wp.p[j])[idx]);
        else         v = ((const float*)wp.p[j])[idx];
        wc[g] = v;
        return;
    }
    blk -= P1_CVTW_BLKS;
    {
        int e = blk * 256 + threadIdx.x;
        if (e < N_EDGES) atomicAdd(&cntI[dstp[e]], 1);
    }
}

// ---- pack job body: basis[5][KL][50] + root[KL][50] -> MFMA B-fragment order
__device__ __forceinline__ void job_pack(int blk, const float* basis, const float* root,
                                         bf16* Wb, int KL) {
    int g = blk * 256 + threadIdx.x;
    int ks = g / 10240;
    int r = g - ks * 10240;
    int ct = r >> 9;
    int r2 = r & 511;
    int l = r2 >> 3, j = r2 & 7;
    int k = ks * 32 + ((l >> 4) << 3) + j;
    int n = ct * 16 + (l & 15);
    float v = 0.f;
    if (k < KL && n < 300) {
        if (n < 250) { int b = n / 50, f = n - b * 50; v = basis[(b * KL + k) * 50 + f]; }
        else         v = root[k * 50 + (n - 250)];
    }
    Wb[g] = f2b(v);
}

// ================= fused prep2: pack1 | pack2 | rel | s1 =====================
__global__ __launch_bounds__(256) void k_prep2(const float* __restrict__ wc,
                                               bf16* __restrict__ Wb1, bf16* __restrict__ Wb2,
                                               float* __restrict__ rt1, float* __restrict__ rt2,
                                               float* __restrict__ c81, float* __restrict__ c82,
                                               const int* __restrict__ cntI,
                                               int* __restrict__ bsum) {
    int blk = blockIdx.x;
    if (blk < P2_PACK1_BLKS) { job_pack(blk, wc + O_BASIS1, wc + O_ROOT1, Wb1, D_IN); return; }
    blk -= P2_PACK1_BLKS;
    if (blk < P2_PACK2_BLKS) { job_pack(blk, wc + O_BASIS2, wc + O_ROOT2, Wb2, D_HID); return; }
    blk -= P2_PACK2_BLKS;
    if (blk < P2_REL_BLKS) {
        const float* rel_emb = wc + O_RELEMB;
        const float* rel_w   = wc + O_RELW;
        const float* basis1  = wc + O_BASIS1;
        const float* comp1   = wc + O_COMP1;
        const float* basis2  = wc + O_BASIS2;
        const float* comp2   = wc + O_COMP2;
        int t = blk;
        int tid = threadIdx.x;
        __shared__ float rf[D_IN];
        __shared__ float r2s[D_HID];
        int tm = (t >= N_REL) ? t - N_REL : t;
        if (tid < D_IN) rf[tid] = rel_emb[tm * D_IN + tid];
        if (tid < 8) {
            c81[t * 8 + tid] = (tid < 5) ? comp1[t * 5 + tid] : 0.f;
            c82[t * 8 + tid] = (tid < 5) ? comp2[t * 5 + tid] : 0.f;
        }
        __syncthreads();
        if (tid < 50) {
            int f = tid;
            float a = 0.f;
            for (int b = 0; b < 5; ++b) {
                float cb = comp1[t * 5 + b];
                float s = 0.f;
                for (int k = 0; k < D_IN; ++k) s += rf[k] * basis1[(b * D_IN + k) * 50 + f];
                a += cb * s;
            }
            rt1[t * 50 + f] = a;
            float s2 = 0.f;
            for (int k = 0; k < D_IN; ++k) s2 += rf[k] * rel_w[k * 50 + f];
            r2s[f] = s2;
        }
        __syncthreads();
        if (tid < 50) {
            int f = tid;
            float a = 0.f;
            for (int b = 0; b < 5; ++b) {
                float cb = comp2[t * 5 + b];
                float s = 0.f;
                for (int k = 0; k < 50; ++k) s += r2s[k] * basis2[(b * 50 + k) * 50 + f];
                a += cb * s;
            }
            rt2[t * 50 + f] = a;
        }
        return;
    }
    blk -= P2_REL_BLKS;
    {
        __shared__ int sh[256];
        int i = blk * 256 + threadIdx.x;
        sh[threadIdx.x] = (i < N_NODES) ? cntI[i] : 0;
        __syncthreads();
        for (int s = 128; s > 0; s >>= 1) {
            if (threadIdx.x < s) sh[threadIdx.x] += sh[threadIdx.x + s];
            __syncthreads();
        }
        if (threadIdx.x == 0) bsum[blk] = sh[0];
    }
}

// single-wave shuffle exclusive scan over NBLK block sums
__global__ void k_s2(int* __restrict__ bsum) {
    int lane = threadIdx.x;   // 64
    int carry = 0;
    for (int c = 0; c < (NBLK + 63) / 64; ++c) {
        int idx = c * 64 + lane;
        int v = (idx < NBLK) ? bsum[idx] : 0;
        int orig = v;
        for (int o = 1; o < 64; o <<= 1) {
            int t = __shfl_up(v, o);
            if (lane >= o) v += t;
        }
        if (idx < NBLK) bsum[idx] = carry + v - orig;
        carry += __shfl(v, 63);
    }
}

__global__ void k_s3(const int* __restrict__ cntI, const int* __restrict__ bsum,
                     int* __restrict__ off) {
    __shared__ int sh[256];
    int i = blockIdx.x * 256 + threadIdx.x;
    int v = (i < N_NODES) ? cntI[i] : 0;
    sh[threadIdx.x] = v;
    __syncthreads();
    for (int s = 1; s < 256; s <<= 1) {
        int t = (threadIdx.x >= (unsigned)s) ? sh[threadIdx.x - s] : 0;
        __syncthreads();
        sh[threadIdx.x] += t;
        __syncthreads();
    }
    int excl = sh[threadIdx.x] - v + bsum[blockIdx.x];
    if (i < N_NODES) off[i] = excl;
    if (i == N_NODES - 1) off[N_NODES] = excl + v;
}

// ================= binned scatter stage 1: edges -> bucket staging ===========
// Packs (dst<<32)|src|et<<17 into per-bucket regions (bucket = dst>>10), with
// per-block LDS counting-sort so staging writes are coalesced runs.
__global__ __launch_bounds__(256) void k_bin(const int* __restrict__ src,
                                             const int* __restrict__ dst,
                                             const int* __restrict__ et,
                                             unsigned* __restrict__ bucketFill,
                                             unsigned long long* __restrict__ staging) {
    __shared__ unsigned lhist[NBUCK];
    __shared__ unsigned lstart[NBUCK];
    __shared__ unsigned gbase[NBUCK];
    __shared__ unsigned scan_tmp[NBUCK];
    __shared__ unsigned long long lval[BIN_EPB];
    __shared__ unsigned ltgt[BIN_EPB];
    int tid = threadIdx.x;
    int base = blockIdx.x * BIN_EPB;
    int n = N_EDGES - base; if (n > BIN_EPB) n = BIN_EPB;

    for (int i = tid; i < NBUCK; i += 256) lhist[i] = 0;
    __syncthreads();

    unsigned bb[4], rr[4];
    unsigned long long vv[4];
#pragma unroll
    for (int j = 0; j < 4; ++j) {
        int i = j * 256 + tid;
        bb[j] = 0xFFFFFFFFu;
        if (i < n) {
            int e = base + i;
            unsigned d = (unsigned)dst[e];
            unsigned b = d >> BSHIFT;
            bb[j] = b;
            rr[j] = atomicAdd(&lhist[b], 1u);
            vv[j] = ((unsigned long long)d << 32) |
                    (unsigned long long)((unsigned)src[e] | ((unsigned)et[e] << 17));
        }
    }
    __syncthreads();
    // exclusive scan of lhist -> lstart; reserve global space per bucket
    unsigned v0 = (tid < NBUCK) ? lhist[tid] : 0;
    if (tid < NBUCK) scan_tmp[tid] = v0;
    __syncthreads();
    for (int s = 1; s < NBUCK; s <<= 1) {
        unsigned t = 0;
        if (tid < NBUCK && tid >= (unsigned)s) t = scan_tmp[tid - s];
        __syncthreads();
        if (tid < NBUCK) scan_tmp[tid] += t;
        __syncthreads();
    }
    if (tid < NBUCK) {
        lstart[tid] = scan_tmp[tid] - v0;
        gbase[tid] = (v0 > 0) ? atomicAdd(&bucketFill[tid], v0) : 0u;
    }
    __syncthreads();
#pragma unroll
    for (int j = 0; j < 4; ++j) {
        if (bb[j] != 0xFFFFFFFFu) {
            unsigned pos = lstart[bb[j]] + rr[j];
            unsigned off = gbase[bb[j]] + rr[j];
            lval[pos] = vv[j];
            ltgt[pos] = (off < BCAP) ? (bb[j] * BCAP + off) : 0xFFFFFFFFu;
        }
    }
    __syncthreads();
    for (int i = tid; i < n; i += 256) {
        unsigned t = ltgt[i];
        if (t != 0xFFFFFFFFu) staging[t] = lval[i];
    }
}

// ================= binned scatter stage 2: staging -> dst-sorted se ==========
// XCD-affine mapping: all 20 blocks of a bucket share blk%8 (same XCD), so
// same-line se writes merge in one L2.
__global__ __launch_bounds__(256) void k_scatter2(const unsigned long long* __restrict__ staging,
                                                  const unsigned* __restrict__ bucketFill,
                                                  const int* __restrict__ offs,
                                                  int* __restrict__ fill,
                                                  unsigned* __restrict__ se) {
    int blk = blockIdx.x;
    int b = (blk / (S2_JPB * 8)) * 8 + (blk & 7);
    int j = (blk % (S2_JPB * 8)) >> 3;      // 0..S2_JPB-1
    unsigned cnt = bucketFill[b]; if (cnt > BCAP) cnt = BCAP;
    unsigned start = (unsigned)j * BIN_EPB;
    if (start >= cnt) return;
    unsigned n = cnt - start; if (n > BIN_EPB) n = BIN_EPB;
    const unsigned long long* p = staging + (size_t)b * BCAP + start;
    for (unsigned i = threadIdx.x; i < n; i += 256) {
        unsigned long long v = p[i];
        int d = (int)(v >> 32);
        int pos = offs[d] + atomicAdd(&fill[d], 1);
        se[pos] = (unsigned)v;
    }
}

// ---- MFMA GEMM: [X @ Wb] -> Y8 (fp8, plane-split 256 B rows) + R (bf16 root)
// Y8 row layout: bytes [0,200): dword f (f=0..49) = fp8 of basis cols {f,50+f,100+f,150+f};
//                bytes [200,250): byte f = fp8 of basis col 200+f (b=4); [250,256) pad.
template<int KP, bool ZT>
__global__ __launch_bounds__(256) void k_gemm_mfma(const bf16* __restrict__ X,
                                                   const bf16* __restrict__ Wb,
                                                   unsigned char* __restrict__ Y8,
                                                   bf16* __restrict__ R, int M,
                                                   const int* __restrict__ tgt) {
    __shared__ bf16 smem[64 * 320];   // 40 KB
    int tid = threadIdx.x;
    int w = tid >> 6, lane = tid & 63;
    int quad = lane >> 4, cIn = lane & 15;
    int base_row = blockIdx.x * 64;

    const int TOT = 64 * KP / 8;
    for (int i = tid; i < TOT; i += 256) {
        int e8 = i * 8;
        int r = e8 / KP, c = e8 - r * KP;
        int row = base_row + r; if (row > M - 1) row = M - 1;
        *(uint4*)(&smem[r * KP + c]) = *(const uint4*)(&X[(size_t)row * KP + c]);
    }
    __syncthreads();

    f32x4 acc[20];
#pragma unroll
    for (int i = 0; i < 20; ++i) acc[i] = (f32x4){0.f, 0.f, 0.f, 0.f};

#pragma unroll
    for (int ks = 0; ks < KP / 32; ++ks) {
        short8 a = *(const short8*)(&smem[(w * 16 + cIn) * KP + ks * 32 + quad * 8]);
#pragma unroll
        for (int ct = 0; ct < 20; ++ct) {
            short8 b = *(const short8*)(&Wb[(size_t)((ks * 20 + ct) * 64 + lane) * 8]);
            acc[ct] = __builtin_amdgcn_mfma_f32_16x16x32_bf16(a, b, acc[ct], 0, 0, 0);
        }
    }
    __syncthreads();

#pragma unroll
    for (int ct = 0; ct < 20; ++ct)
#pragma unroll
        for (int r = 0; r < 4; ++r)
            smem[(w * 16 + quad * 4 + r) * 320 + ct * 16 + cIn] = f2b(acc[ct][r]);
    __syncthreads();

    int tv = -1;
    if (ZT) tv = tgt[0];
    int valid = M - base_row; if (valid > 64) valid = 64;

    for (int i = tid; i < valid * 64; i += 256) {
        int r = i >> 6, u = i & 63;
        int row = base_row + r;
        unsigned pbits;
        if (u < 50) {
            pbits = pk4_f8(b2f(smem[r * 320 + u]),       b2f(smem[r * 320 + 50 + u]),
                           b2f(smem[r * 320 + 100 + u]), b2f(smem[r * 320 + 150 + u]));
        } else if (u < 63) {
            int fb = (u - 50) * 4;
            float v0 = (fb + 0 < 50) ? b2f(smem[r * 320 + 200 + fb + 0]) : 0.f;
            float v1 = (fb + 1 < 50) ? b2f(smem[r * 320 + 200 + fb + 1]) : 0.f;
            float v2 = (fb + 2 < 50) ? b2f(smem[r * 320 + 200 + fb + 2]) : 0.f;
            float v3 = (fb + 3 < 50) ? b2f(smem[r * 320 + 200 + fb + 3]) : 0.f;
            pbits = pk4_f8(v0, v1, v2, v3);
        } else {
            pbits = 0u;
        }
        if (ZT && row == tv) pbits = 0u;
        *(unsigned*)(Y8 + (size_t)row * 256 + u * 4) = pbits;
    }
    for (int i = tid; i < valid * 32; i += 256) {
        int r = i >> 5, cu = i & 31;
        int row = base_row + r;
        int j0 = cu * 2, j1 = j0 + 1;
        unsigned short ua = (j0 < 50) ? *(const unsigned short*)&smem[r * 320 + 250 + j0] : 0;
        unsigned short ub = (j1 < 50) ? *(const unsigned short*)&smem[r * 320 + 250 + j1] : 0;
        unsigned u = (unsigned)ua | ((unsigned)ub << 16);
        if (ZT && row == tv) u = 0u;
        *(unsigned*)((unsigned short*)R + (size_t)row * 64 + j0) = u;
    }
}

// ================= per-node gather-reduce (no atomics) =======================
// Per edge/lane: Y8 dword + Y8 byte + c8 dwordx4 + c8 dword + rt dword (VMEM 5),
// 2 pk-cvt + 1 cvt, float2 math (pk_fma candidates).
#define EDGE_BODY(p, ACC2, ACCS)                                              \
    {                                                                         \
        int s_ = __builtin_amdgcn_readfirstlane((int)((p) & 0x1FFFFu));       \
        int t_ = __builtin_amdgcn_readfirstlane((int)((p) >> 17));            \
        const unsigned char* yr_ = Y8 + (size_t)s_ * 256;                     \
        unsigned a4_ = *(const unsigned*)(yr_ + 4 * f);                       \
        float y4_ = f8tof(yr_[200 + f]);                                      \
        const float* cp_ = c8 + t_ * 8;                                       \
        f32x4 c03_ = *(const f32x4*)cp_;                                      \
        float c4_ = cp_[4];                                                   \
        float rv_ = rt[t_ * 50 + f];                                          \
        f32x2 y01_ = f8pk<false>(a4_);                                        \
        f32x2 y23_ = f8pk<true>(a4_);                                         \
        f32x2 cA_; cA_.x = c03_.x; cA_.y = c03_.y;                            \
        f32x2 cB_; cB_.x = c03_.z; cB_.y = c03_.w;                            \
        ACC2 += cA_ * y01_;                                                   \
        ACC2 += cB_ * y23_;                                                   \
        ACCS += rv_ + c4_ * y4_;                                              \
    }

#define REDUCE_LOOP                                                           \
    f32x2 acc2; acc2.x = 0.f; acc2.y = 0.f;                                   \
    float accS = 0.f;                                                         \
    int e = e0;                                                               \
    for (; e + 8 <= e1; e += 8) {                                             \
        unsigned p0 = se[e],     p1 = se[e + 1], p2 = se[e + 2], p3 = se[e + 3]; \
        unsigned p4 = se[e + 4], p5 = se[e + 5], p6 = se[e + 6], p7 = se[e + 7]; \
        EDGE_BODY(p0, acc2, accS) EDGE_BODY(p1, acc2, accS)                   \
        EDGE_BODY(p2, acc2, accS) EDGE_BODY(p3, acc2, accS)                   \
        EDGE_BODY(p4, acc2, accS) EDGE_BODY(p5, acc2, accS)                   \
        EDGE_BODY(p6, acc2, accS) EDGE_BODY(p7, acc2, accS)                   \
    }                                                                         \
    for (; e < e1; ++e) {                                                     \
        unsigned p = se[e];                                                   \
        EDGE_BODY(p, acc2, accS)                                              \
    }                                                                         \
    float acc = acc2.x + acc2.y + accS;

// Layer 1: h[row][0..63] = mean_agg + x@root (R) + bias (cols>=50 zero)
__global__ __launch_bounds__(256) void k_reduce1(const int* __restrict__ off,
                                                 const unsigned int* __restrict__ se,
                                                 const float* __restrict__ c8,
                                                 const float* __restrict__ rt,
                                                 const unsigned char* __restrict__ Y8,
                                                 const bf16* __restrict__ R,
                                                 const float* __restrict__ bias_,
                                                 bf16* __restrict__ h) {
    int wid = threadIdx.x >> 6, lane = threadIdx.x & 63;
    int row = blockIdx.x * 4 + wid;
    if (row >= N_NODES) return;
    int e0 = off[row], e1 = off[row + 1];
    int f = (lane < 50) ? lane : 49;
    REDUCE_LOOP
    float c = (float)(e1 - e0); c = c > 1.f ? c : 1.f;
    float v = acc / c + b2f(R[(size_t)row * 64 + f]) + bias_[f];
    h[(size_t)row * 64 + lane] = f2b(lane < 50 ? v : 0.f);
}

// Layer 2: same reduce + log_softmax epilogue; dual-dtype output store.
__global__ __launch_bounds__(256) void k_reduce2(const int* __restrict__ off,
                                                 const unsigned int* __restrict__ se,
                                                 const float* __restrict__ c8,
                                                 const float* __restrict__ rt,
                                                 const unsigned char* __restrict__ Y8,
                                                 const bf16* __restrict__ R,
                                                 const float* __restrict__ bias_,
                                                 const int* __restrict__ flag,
                                                 void* __restrict__ out) {
    int wid = threadIdx.x >> 6, lane = threadIdx.x & 63;
    int row = blockIdx.x * 4 + wid;
    if (row >= N_NODES) return;
    int e0 = off[row], e1 = off[row + 1];
    int f = (lane < 50) ? lane : 49;
    REDUCE_LOOP
    float c = (float)(e1 - e0); c = c > 1.f ? c : 1.f;
    float v = -INFINITY;
    if (lane < 50)
        v = acc / c + b2f(R[(size_t)row * 64 + f]) + bias_[f];
    float m = v;
    for (int o = 32; o > 0; o >>= 1) m = fmaxf(m, __shfl_xor(m, o));
    float ex = (lane < 50) ? expf(v - m) : 0.f;
    float s = ex;
    for (int o = 32; o > 0; o >>= 1) s += __shfl_xor(s, o);
    float res = v - m - logf(s);
    if (lane < 50) {
        if (flag[0]) ((bf16*)out)[row * 50 + f] = f2b(res);
        else         ((float*)out)[row * 50 + f] = res;
    }
}

extern "C" void kernel_launch(void* const* d_in, const int* in_sizes, int n_in,
                              void* d_out, int out_size, void* d_ws, size_t ws_size,
                              hipStream_t stream) {
    const void* x_raw = d_in[0];
    const int*  ei    = (const int*)d_in[1];
    const int*  et    = (const int*)d_in[2];
    const int*  tgt   = (const int*)d_in[3];

    char* wsp = (char*)d_ws;
    size_t off_b = 0;
    auto alloc = [&](size_t bytes) {
        void* p = wsp + off_b;
        off_b = (off_b + bytes + 255) & ~(size_t)255;
        return p;
    };
    unsigned char* Y8 = (unsigned char*)alloc((size_t)N_NODES * 256);       // 25.6 MB
    bf16*  R    = (bf16*) alloc((size_t)N_NODES * 64 * sizeof(bf16));       // 12.8 MB
    bf16*  xc   = (bf16*) alloc((size_t)N_NODES * 128 * sizeof(bf16));      // 25.6 MB
    bf16*  h    = xc;   // alias: xc dead after layer-1 GEMM
    unsigned int* se = (unsigned int*)alloc((size_t)N_EDGES * sizeof(unsigned int)); // 6.4 MB
    unsigned long long* staging = (unsigned long long*)alloc((size_t)NBUCK * BCAP * 8); // 21 MB
    int*   cntI = (int*)  alloc((size_t)N_NODES * sizeof(int));
    int*   offs = (int*)  alloc((size_t)(N_NODES + 1) * sizeof(int));
    int*   fill = (int*)  alloc((size_t)(N_NODES + NBUCK) * sizeof(int));
    unsigned* bucketFill = (unsigned*)(fill + N_NODES);
    int*   bsum = (int*)  alloc((size_t)NBLK * sizeof(int));
    float* wc   = (float*)alloc((size_t)W_TOTAL * sizeof(float));
    bf16*  Wb1  = (bf16*) alloc((size_t)40960 * sizeof(bf16));
    bf16*  Wb2  = (bf16*) alloc((size_t)20480 * sizeof(bf16));
    float* rt1  = (float*)alloc((size_t)N_REL2 * 50 * sizeof(float));
    float* rt2  = (float*)alloc((size_t)N_REL2 * 50 * sizeof(float));
    float* c81  = (float*)alloc((size_t)N_REL2 * 8 * sizeof(float));
    float* c82  = (float*)alloc((size_t)N_REL2 * 8 * sizeof(float));
    int*   flag = (int*)  alloc(sizeof(int));

    const int* srcp = ei;
    const int* dstp = ei + N_EDGES;

    hipMemsetAsync(cntI, 0, (size_t)N_NODES * sizeof(int), stream);
    hipMemsetAsync(fill, 0, (size_t)(N_NODES + NBUCK) * sizeof(int), stream);

    WPtrs wp;
    for (int i = 0; i < 10; ++i) wp.p[i] = d_in[4 + i];

    k_detect<<<1, 256, 0, stream>>>((const unsigned short*)x_raw, flag);
    k_prep1<<<P1_TOTAL, 256, 0, stream>>>(x_raw, flag, xc, wp, wc, dstp, cntI);
    k_bin<<<BIN_BLKS, 256, 0, stream>>>(srcp, dstp, et, bucketFill, staging);
    k_prep2<<<P2_TOTAL, 256, 0, stream>>>(wc, Wb1, Wb2, rt1, rt2, c81, c82, cntI, bsum);
    k_s2<<<1, 64, 0, stream>>>(bsum);
    k_s3<<<NBLK, 256, 0, stream>>>(cntI, bsum, offs);
    k_scatter2<<<NBUCK * S2_JPB, 256, 0, stream>>>(staging, bucketFill, offs, fill, se);

    // Layer 1
    k_gemm_mfma<128, true><<<(N_NODES + 63) / 64, 256, 0, stream>>>(xc, Wb1, Y8, R, N_NODES, tgt);
    k_reduce1<<<(N_NODES + 3) / 4, 256, 0, stream>>>(offs, se, c81, rt1, Y8, R, wc + O_BIAS1, h);

    // Layer 2
    k_gemm_mfma<64, false><<<(N_NODES + 63) / 64, 256, 0, stream>>>(h, Wb2, Y8, R, N_NODES, nullptr);
    k_reduce2<<<(N_NODES + 3) / 4, 256, 0, stream>>>(offs, se, c82, rt2, Y8, R, wc + O_BIAS2, flag, d_out);
}

// Round 9
// 476.471 us; speedup vs baseline: 5.5499x; 1.2151x over previous
//
#include <hip/hip_runtime.h>
#include <hip/hip_bf16.h>

typedef __hip_bfloat16 bf16;

#define N_NODES 100000
#define N_EDGES 1600000
#define D_IN    100
#define D_HID   50
#define N_REL   237
#define N_REL2  474
#define N_CLASS 50

// Canonical fp32 weight-block offsets (element offsets into wc)
#define O_RELEMB 0
#define O_RELW   23700
#define O_BASIS1 28700
#define O_COMP1  53700
#define O_ROOT1  56070
#define O_BIAS1  61070
#define O_BASIS2 61120
#define O_COMP2  73620
#define O_ROOT2  75990
#define O_BIAS2  78490
#define W_TOTAL  78540

// binned scatter
#define NBUCK    128
#define BSHIFT   10
#define BCAP     20480                // mean 16.4K, sigma ~127 -> 32 sigma headroom
#define BIN_EPB  1024
#define BIN_BLKS ((N_EDGES + BIN_EPB - 1) / BIN_EPB)   // 1563

// prep1 grid partition (256-thread blocks): convert_x | convert_w | bin
#define P1_CVTX_BLKS 50000            // N_NODES*128/256
#define P1_CVTW_BLKS 307              // ceil(W_TOTAL/256)
#define P1_TOTAL (P1_CVTX_BLKS + P1_CVTW_BLKS + BIN_BLKS)

// prep2 grid partition: pack1 | pack2 | rel
#define P2_PACK1_BLKS 160             // 4 ksteps * 10240 / 256
#define P2_PACK2_BLKS 80
#define P2_REL_BLKS   474
#define P2_TOTAL (P2_PACK1_BLKS + P2_PACK2_BLKS + P2_REL_BLKS)

typedef __attribute__((ext_vector_type(8))) short short8;
typedef __attribute__((ext_vector_type(4))) float f32x4;
typedef __attribute__((ext_vector_type(2))) float f32x2;

__device__ __forceinline__ float b2f(bf16 v) { return __bfloat162float(v); }
__device__ __forceinline__ bf16  f2b(float v) { return __float2bfloat16(v); }

#if __has_builtin(__builtin_amdgcn_cvt_f32_fp8) && __has_builtin(__builtin_amdgcn_cvt_pk_fp8_f32)
#define F8_HW 1
#endif
#if __has_builtin(__builtin_amdgcn_cvt_pk_f32_fp8)
#define F8PK_HW 1
#endif

// ---- fp8 e4m3 (OCP, gfx950 HW) helpers ----
__device__ __forceinline__ float f8tof(unsigned u) {
#ifdef F8_HW
    return __builtin_amdgcn_cvt_f32_fp8((int)u, 0);
#else
    unsigned s = u >> 7, e = (u >> 3) & 0xF, m = u & 7;
    float v;
    if (e == 0) v = (float)m * 0.001953125f;
    else        v = (float)(8 + m) * __builtin_ldexpf(1.f, (int)e - 10);
    return s ? -v : v;
#endif
}

#ifdef F8_HW
#define F8SEL(u, s) __builtin_amdgcn_cvt_f32_fp8((int)(u), (s))
#else
#define F8SEL(u, s) f8tof(((u) >> (8 * (s))) & 0xFFu)
#endif

template <bool HI>
__device__ __forceinline__ f32x2 f8pk(unsigned u) {
#ifdef F8PK_HW
    return __builtin_amdgcn_cvt_pk_f32_fp8((int)u, HI);
#else
    f32x2 r;
    r.x = F8SEL(u, HI ? 2 : 0);
    r.y = F8SEL(u, HI ? 3 : 1);
    return r;
#endif
}

__device__ __forceinline__ unsigned f8enc_sw(float v) {
    unsigned bits = __float_as_uint(v);
    unsigned s = bits >> 31;
    float a = fabsf(v);
    if (a < 0.0009765625f) return s << 7;
    if (a >= 448.f) return (s << 7) | 0x7E;
    int E = (int)((bits >> 23) & 0xFF) - 127;
    unsigned m = bits & 0x7FFFFF;
    if (E < -6) {
        int q = (int)rintf(a * 512.f);
        if (q > 7) q = 7;
        return (s << 7) | (unsigned)q;
    }
    unsigned lsb = (m >> 20) & 1, rnd = (m >> 19) & 1;
    unsigned sticky = (m & 0x7FFFF) ? 1u : 0u;
    unsigned m3 = (m >> 20) + (rnd & (sticky | lsb));
    if (m3 == 8) { m3 = 0; E += 1; }
    if (E > 8) return (s << 7) | 0x7E;
    return (s << 7) | ((unsigned)(E + 7) << 3) | m3;
}

__device__ __forceinline__ unsigned pk4_f8(float v0, float v1, float v2, float v3) {
#ifdef F8_HW
    int p = __builtin_amdgcn_cvt_pk_fp8_f32(v0, v1, 0, false);
    p = __builtin_amdgcn_cvt_pk_fp8_f32(v2, v3, p, true);
    return (unsigned)p;
#else
    return f8enc_sw(v0) | (f8enc_sw(v1) << 8) | (f8enc_sw(v2) << 16) | (f8enc_sw(v3) << 24);
#endif
}

// ---- dtype detection: flag[0]=1 if float arrays are stored as bf16, 0 if fp32.
__global__ void k_detect(const unsigned short* __restrict__ xr, int* __restrict__ flag) {
    int tid = threadIdx.x;
    int cnt = 0;
    for (int i = tid; i < 4096; i += 256) {
        unsigned short u = xr[2 * i];
        unsigned e = (u >> 7) & 0xFF;
        bool pl = (e >= 107 && e <= 132) || ((u & 0x7FFF) == 0);
        cnt += pl ? 1 : 0;
    }
    __shared__ int sh[256];
    sh[tid] = cnt;
    __syncthreads();
    for (int s = 128; s > 0; s >>= 1) {
        if (tid < s) sh[tid] += sh[tid + s];
        __syncthreads();
    }
    if (tid == 0) flag[0] = (sh[0] >= 3072) ? 1 : 0;
}

struct WPtrs { const void* p[10]; };

// ---- bin job: per-block LDS counting-sort of 1024 edges into bucket staging
__device__ __forceinline__ void job_bin(int blk, const int* __restrict__ src,
                                        const int* __restrict__ dst,
                                        const int* __restrict__ et,
                                        unsigned* __restrict__ bucketFill,
                                        unsigned long long* __restrict__ staging) {
    __shared__ unsigned lhist[NBUCK];
    __shared__ unsigned lstart[NBUCK];
    __shared__ unsigned gbase[NBUCK];
    __shared__ unsigned scan_tmp[NBUCK];
    __shared__ unsigned long long lval[BIN_EPB];
    __shared__ unsigned ltgt[BIN_EPB];
    int tid = threadIdx.x;
    int base = blk * BIN_EPB;
    int n = N_EDGES - base; if (n > BIN_EPB) n = BIN_EPB;

    for (int i = tid; i < NBUCK; i += 256) lhist[i] = 0;
    __syncthreads();

    unsigned bb[4], rr[4];
    unsigned long long vv[4];
#pragma unroll
    for (int j = 0; j < 4; ++j) {
        int i = j * 256 + tid;
        bb[j] = 0xFFFFFFFFu;
        if (i < n) {
            int e = base + i;
            unsigned d = (unsigned)dst[e];
            unsigned b = d >> BSHIFT;
            bb[j] = b;
            rr[j] = atomicAdd(&lhist[b], 1u);
            vv[j] = ((unsigned long long)d << 32) |
                    (unsigned long long)((unsigned)src[e] | ((unsigned)et[e] << 17));
        }
    }
    __syncthreads();
    unsigned v0 = (tid < NBUCK) ? lhist[tid] : 0;
    if (tid < NBUCK) scan_tmp[tid] = v0;
    __syncthreads();
    for (int s = 1; s < NBUCK; s <<= 1) {
        unsigned t = 0;
        if (tid < NBUCK && tid >= (unsigned)s) t = scan_tmp[tid - s];
        __syncthreads();
        if (tid < NBUCK) scan_tmp[tid] += t;
        __syncthreads();
    }
    if (tid < NBUCK) {
        lstart[tid] = scan_tmp[tid] - v0;
        gbase[tid] = (v0 > 0) ? atomicAdd(&bucketFill[tid], v0) : 0u;
    }
    __syncthreads();
#pragma unroll
    for (int j = 0; j < 4; ++j) {
        if (bb[j] != 0xFFFFFFFFu) {
            unsigned pos = lstart[bb[j]] + rr[j];
            unsigned off = gbase[bb[j]] + rr[j];
            lval[pos] = vv[j];
            ltgt[pos] = (off < BCAP) ? (bb[j] * BCAP + off) : 0xFFFFFFFFu;
        }
    }
    __syncthreads();
    for (int i = tid; i < n; i += 256) {
        unsigned t = ltgt[i];
        if (t != 0xFFFFFFFFu) staging[t] = lval[i];
    }
}

// ================= fused prep1: convert_x | convert_w | bin ==================
__global__ __launch_bounds__(256) void k_prep1(const void* __restrict__ xr,
                                               const int* __restrict__ flag,
                                               bf16* __restrict__ xc,
                                               WPtrs wp, float* __restrict__ wc,
                                               const int* __restrict__ srcp,
                                               const int* __restrict__ dstp,
                                               const int* __restrict__ etp,
                                               unsigned* __restrict__ bucketFill,
                                               unsigned long long* __restrict__ staging) {
    int blk = blockIdx.x;
    if (blk < P1_CVTX_BLKS) {
        int g = blk * 256 + threadIdx.x;
        int row = g >> 7, col = g & 127;
        bf16 o = f2b(0.f);
        if (col < D_IN) {
            if (flag[0]) o = ((const bf16*)xr)[row * D_IN + col];
            else         o = f2b(((const float*)xr)[row * D_IN + col]);
        }
        xc[g] = o;
        return;
    }
    blk -= P1_CVTX_BLKS;
    if (blk < P1_CVTW_BLKS) {
        const int sz[10] = {23700, 5000, 25000, 2370, 5000, 50, 12500, 2370, 2500, 50};
        int g = blk * 256 + threadIdx.x;
        if (g >= W_TOTAL) return;
        int j = 0, base = 0;
        while (j < 9 && g >= base + sz[j]) { base += sz[j]; ++j; }
        int idx = g - base;
        float v;
        if (flag[0]) v = b2f(((const bf16*)wp.p[j])[idx]);
        else         v = ((const float*)wp.p[j])[idx];
        wc[g] = v;
        return;
    }
    blk -= P1_CVTW_BLKS;
    job_bin(blk, srcp, dstp, etp, bucketFill, staging);
}

// ================= per-bucket CSR build: offs + se, zero global atomics ======
// One 1024-thread block per bucket. LDS histogram -> scan -> coalesced offs
// write; rank pass scatters se into the bucket's contiguous window (L2-local).
__global__ __launch_bounds__(1024) void k_bucket(const unsigned long long* __restrict__ staging,
                                                 const unsigned* __restrict__ bucketFill,
                                                 int* __restrict__ offs,
                                                 unsigned* __restrict__ se) {
    __shared__ unsigned hist[1024];
    __shared__ unsigned excl[1024];
    __shared__ unsigned bfs[NBUCK];
    int tid = threadIdx.x;
    int b = blockIdx.x;

    if (tid < NBUCK) {
        unsigned c = bucketFill[tid];
        bfs[tid] = (c > BCAP) ? BCAP : c;
    }
    hist[tid] = 0;
    __syncthreads();
    // scan bucket totals (inclusive) to get this bucket's global base
    for (int s = 1; s < NBUCK; s <<= 1) {
        unsigned t = 0;
        if (tid < NBUCK && tid >= (unsigned)s) t = bfs[tid - s];
        __syncthreads();
        if (tid < NBUCK) bfs[tid] += t;
        __syncthreads();
    }
    unsigned base = (b == 0) ? 0u : bfs[b - 1];
    unsigned cnt = bfs[b] - base;

    const unsigned long long* p = staging + (size_t)b * BCAP;
    // pass 1: per-node histogram (local id = dst & 1023)
    for (unsigned i = tid; i < cnt; i += 1024) {
        unsigned d = (unsigned)(p[i] >> 32);
        atomicAdd(&hist[d & 1023], 1u);
    }
    __syncthreads();
    // inclusive scan of 1024 node counts
    excl[tid] = hist[tid];
    __syncthreads();
    for (int s = 1; s < 1024; s <<= 1) {
        unsigned t = (tid >= s) ? excl[tid - s] : 0u;
        __syncthreads();
        excl[tid] += t;
        __syncthreads();
    }
    unsigned my_excl = excl[tid] - hist[tid];
    __syncthreads();
    excl[tid] = my_excl;
    hist[tid] = 0;                      // reset for rank pass
    __syncthreads();

    int node = b * 1024 + tid;
    if (node < N_NODES) offs[node] = (int)(base + my_excl);
    if (node == N_NODES - 1) offs[N_NODES] = (int)(base + cnt);

    // pass 2: scatter with per-node rank
    for (unsigned i = tid; i < cnt; i += 1024) {
        unsigned long long v = p[i];
        unsigned ld = ((unsigned)(v >> 32)) & 1023u;
        unsigned r = atomicAdd(&hist[ld], 1u);
        se[base + excl[ld] + r] = (unsigned)v;
    }
}

// ---- pack job body: basis[5][KL][50] + root[KL][50] -> MFMA B-fragment order
__device__ __forceinline__ void job_pack(int blk, const float* basis, const float* root,
                                         bf16* Wb, int KL) {
    int g = blk * 256 + threadIdx.x;
    int ks = g / 10240;
    int r = g - ks * 10240;
    int ct = r >> 9;
    int r2 = r & 511;
    int l = r2 >> 3, j = r2 & 7;
    int k = ks * 32 + ((l >> 4) << 3) + j;
    int n = ct * 16 + (l & 15);
    float v = 0.f;
    if (k < KL && n < 300) {
        if (n < 250) { int b = n / 50, f = n - b * 50; v = basis[(b * KL + k) * 50 + f]; }
        else         v = root[k * 50 + (n - 250)];
    }
    Wb[g] = f2b(v);
}

// ================= fused prep2: pack1 | pack2 | rel ==========================
__global__ __launch_bounds__(256) void k_prep2(const float* __restrict__ wc,
                                               bf16* __restrict__ Wb1, bf16* __restrict__ Wb2,
                                               float* __restrict__ rt1, float* __restrict__ rt2,
                                               float* __restrict__ c81, float* __restrict__ c82) {
    int blk = blockIdx.x;
    if (blk < P2_PACK1_BLKS) { job_pack(blk, wc + O_BASIS1, wc + O_ROOT1, Wb1, D_IN); return; }
    blk -= P2_PACK1_BLKS;
    if (blk < P2_PACK2_BLKS) { job_pack(blk, wc + O_BASIS2, wc + O_ROOT2, Wb2, D_HID); return; }
    blk -= P2_PACK2_BLKS;
    {
        const float* rel_emb = wc + O_RELEMB;
        const float* rel_w   = wc + O_RELW;
        const float* basis1  = wc + O_BASIS1;
        const float* comp1   = wc + O_COMP1;
        const float* basis2  = wc + O_BASIS2;
        const float* comp2   = wc + O_COMP2;
        int t = blk;
        int tid = threadIdx.x;
        __shared__ float rf[D_IN];
        __shared__ float r2s[D_HID];
        int tm = (t >= N_REL) ? t - N_REL : t;
        if (tid < D_IN) rf[tid] = rel_emb[tm * D_IN + tid];
        if (tid < 8) {
            c81[t * 8 + tid] = (tid < 5) ? comp1[t * 5 + tid] : 0.f;
            c82[t * 8 + tid] = (tid < 5) ? comp2[t * 5 + tid] : 0.f;
        }
        __syncthreads();
        if (tid < 50) {
            int f = tid;
            float a = 0.f;
            for (int b = 0; b < 5; ++b) {
                float cb = comp1[t * 5 + b];
                float s = 0.f;
                for (int k = 0; k < D_IN; ++k) s += rf[k] * basis1[(b * D_IN + k) * 50 + f];
                a += cb * s;
            }
            rt1[t * 50 + f] = a;
            float s2 = 0.f;
            for (int k = 0; k < D_IN; ++k) s2 += rf[k] * rel_w[k * 50 + f];
            r2s[f] = s2;
        }
        __syncthreads();
        if (tid < 50) {
            int f = tid;
            float a = 0.f;
            for (int b = 0; b < 5; ++b) {
                float cb = comp2[t * 5 + b];
                float s = 0.f;
                for (int k = 0; k < 50; ++k) s += r2s[k] * basis2[(b * 50 + k) * 50 + f];
                a += cb * s;
            }
            rt2[t * 50 + f] = a;
        }
    }
}

// ---- MFMA GEMM: [X @ Wb] -> Y8 (fp8, plane-split 256 B rows) + R (bf16 root)
// Y8 row layout: bytes [0,200): dword f (f=0..49) = fp8 of basis cols {f,50+f,100+f,150+f};
//                bytes [200,250): byte f = fp8 of basis col 200+f (b=4); [250,256) pad.
template<int KP, bool ZT>
__global__ __launch_bounds__(256) void k_gemm_mfma(const bf16* __restrict__ X,
                                                   const bf16* __restrict__ Wb,
                                                   unsigned char* __restrict__ Y8,
                                                   bf16* __restrict__ R, int M,
                                                   const int* __restrict__ tgt) {
    __shared__ bf16 smem[64 * 320];   // 40 KB
    int tid = threadIdx.x;
    int w = tid >> 6, lane = tid & 63;
    int quad = lane >> 4, cIn = lane & 15;
    int base_row = blockIdx.x * 64;

    const int TOT = 64 * KP / 8;
    for (int i = tid; i < TOT; i += 256) {
        int e8 = i * 8;
        int r = e8 / KP, c = e8 - r * KP;
        int row = base_row + r; if (row > M - 1) row = M - 1;
        *(uint4*)(&smem[r * KP + c]) = *(const uint4*)(&X[(size_t)row * KP + c]);
    }
    __syncthreads();

    f32x4 acc[20];
#pragma unroll
    for (int i = 0; i < 20; ++i) acc[i] = (f32x4){0.f, 0.f, 0.f, 0.f};

#pragma unroll
    for (int ks = 0; ks < KP / 32; ++ks) {
        short8 a = *(const short8*)(&smem[(w * 16 + cIn) * KP + ks * 32 + quad * 8]);
#pragma unroll
        for (int ct = 0; ct < 20; ++ct) {
            short8 b = *(const short8*)(&Wb[(size_t)((ks * 20 + ct) * 64 + lane) * 8]);
            acc[ct] = __builtin_amdgcn_mfma_f32_16x16x32_bf16(a, b, acc[ct], 0, 0, 0);
        }
    }
    __syncthreads();

#pragma unroll
    for (int ct = 0; ct < 20; ++ct)
#pragma unroll
        for (int r = 0; r < 4; ++r)
            smem[(w * 16 + quad * 4 + r) * 320 + ct * 16 + cIn] = f2b(acc[ct][r]);
    __syncthreads();

    int tv = -1;
    if (ZT) tv = tgt[0];
    int valid = M - base_row; if (valid > 64) valid = 64;

    for (int i = tid; i < valid * 64; i += 256) {
        int r = i >> 6, u = i & 63;
        int row = base_row + r;
        unsigned pbits;
        if (u < 50) {
            pbits = pk4_f8(b2f(smem[r * 320 + u]),       b2f(smem[r * 320 + 50 + u]),
                           b2f(smem[r * 320 + 100 + u]), b2f(smem[r * 320 + 150 + u]));
        } else if (u < 63) {
            int fb = (u - 50) * 4;
            float v0 = (fb + 0 < 50) ? b2f(smem[r * 320 + 200 + fb + 0]) : 0.f;
            float v1 = (fb + 1 < 50) ? b2f(smem[r * 320 + 200 + fb + 1]) : 0.f;
            float v2 = (fb + 2 < 50) ? b2f(smem[r * 320 + 200 + fb + 2]) : 0.f;
            float v3 = (fb + 3 < 50) ? b2f(smem[r * 320 + 200 + fb + 3]) : 0.f;
            pbits = pk4_f8(v0, v1, v2, v3);
        } else {
            pbits = 0u;
        }
        if (ZT && row == tv) pbits = 0u;
        *(unsigned*)(Y8 + (size_t)row * 256 + u * 4) = pbits;
    }
    for (int i = tid; i < valid * 32; i += 256) {
        int r = i >> 5, cu = i & 31;
        int row = base_row + r;
        int j0 = cu * 2, j1 = j0 + 1;
        unsigned short ua = (j0 < 50) ? *(const unsigned short*)&smem[r * 320 + 250 + j0] : 0;
        unsigned short ub = (j1 < 50) ? *(const unsigned short*)&smem[r * 320 + 250 + j1] : 0;
        unsigned u = (unsigned)ua | ((unsigned)ub << 16);
        if (ZT && row == tv) u = 0u;
        *(unsigned*)((unsigned short*)R + (size_t)row * 64 + j0) = u;
    }
}

// ================= per-node gather-reduce (no atomics) =======================
#define EDGE_BODY(p, ACC2, ACCS)                                              \
    {                                                                         \
        int s_ = __builtin_amdgcn_readfirstlane((int)((p) & 0x1FFFFu));       \
        int t_ = __builtin_amdgcn_readfirstlane((int)((p) >> 17));            \
        const unsigned char* yr_ = Y8 + (size_t)s_ * 256;                     \
        unsigned a4_ = *(const unsigned*)(yr_ + 4 * f);                       \
        float y4_ = f8tof(yr_[200 + f]);                                      \
        const float* cp_ = c8 + t_ * 8;                                       \
        f32x4 c03_ = *(const f32x4*)cp_;                                      \
        float c4_ = cp_[4];                                                   \
        float rv_ = rt[t_ * 50 + f];                                          \
        f32x2 y01_ = f8pk<false>(a4_);                                        \
        f32x2 y23_ = f8pk<true>(a4_);                                         \
        f32x2 cA_; cA_.x = c03_.x; cA_.y = c03_.y;                            \
        f32x2 cB_; cB_.x = c03_.z; cB_.y = c03_.w;                            \
        ACC2 += cA_ * y01_;                                                   \
        ACC2 += cB_ * y23_;                                                   \
        ACCS += rv_ + c4_ * y4_;                                              \
    }

#define REDUCE_LOOP                                                           \
    f32x2 acc2; acc2.x = 0.f; acc2.y = 0.f;                                   \
    float accS = 0.f;                                                         \
    int e = e0;                                                               \
    for (; e + 8 <= e1; e += 8) {                                             \
        unsigned p0 = se[e],     p1 = se[e + 1], p2 = se[e + 2], p3 = se[e + 3]; \
        unsigned p4 = se[e + 4], p5 = se[e + 5], p6 = se[e + 6], p7 = se[e + 7]; \
        EDGE_BODY(p0, acc2, accS) EDGE_BODY(p1, acc2, accS)                   \
        EDGE_BODY(p2, acc2, accS) EDGE_BODY(p3, acc2, accS)                   \
        EDGE_BODY(p4, acc2, accS) EDGE_BODY(p5, acc2, accS)                   \
        EDGE_BODY(p6, acc2, accS) EDGE_BODY(p7, acc2, accS)                   \
    }                                                                         \
    for (; e < e1; ++e) {                                                     \
        unsigned p = se[e];                                                   \
        EDGE_BODY(p, acc2, accS)                                              \
    }                                                                         \
    float acc = acc2.x + acc2.y + accS;

// Layer 1: h[row][0..63] = mean_agg + x@root (R) + bias (cols>=50 zero)
__global__ __launch_bounds__(256) void k_reduce1(const int* __restrict__ off,
                                                 const unsigned int* __restrict__ se,
                                                 const float* __restrict__ c8,
                                                 const float* __restrict__ rt,
                                                 const unsigned char* __restrict__ Y8,
                                                 const bf16* __restrict__ R,
                                                 const float* __restrict__ bias_,
                                                 bf16* __restrict__ h) {
    int wid = threadIdx.x >> 6, lane = threadIdx.x & 63;
    int row = blockIdx.x * 4 + wid;
    if (row >= N_NODES) return;
    int e0 = off[row], e1 = off[row + 1];
    int f = (lane < 50) ? lane : 49;
    REDUCE_LOOP
    float c = (float)(e1 - e0); c = c > 1.f ? c : 1.f;
    float v = acc / c + b2f(R[(size_t)row * 64 + f]) + bias_[f];
    h[(size_t)row * 64 + lane] = f2b(lane < 50 ? v : 0.f);
}

// Layer 2: same reduce + log_softmax epilogue; dual-dtype output store.
__global__ __launch_bounds__(256) void k_reduce2(const int* __restrict__ off,
                                                 const unsigned int* __restrict__ se,
                                                 const float* __restrict__ c8,
                                                 const float* __restrict__ rt,
                                                 const unsigned char* __restrict__ Y8,
                                                 const bf16* __restrict__ R,
                                                 const float* __restrict__ bias_,
                                                 const int* __restrict__ flag,
                                                 void* __restrict__ out) {
    int wid = threadIdx.x >> 6, lane = threadIdx.x & 63;
    int row = blockIdx.x * 4 + wid;
    if (row >= N_NODES) return;
    int e0 = off[row], e1 = off[row + 1];
    int f = (lane < 50) ? lane : 49;
    REDUCE_LOOP
    float c = (float)(e1 - e0); c = c > 1.f ? c : 1.f;
    float v = -INFINITY;
    if (lane < 50)
        v = acc / c + b2f(R[(size_t)row * 64 + f]) + bias_[f];
    float m = v;
    for (int o = 32; o > 0; o >>= 1) m = fmaxf(m, __shfl_xor(m, o));
    float ex = (lane < 50) ? expf(v - m) : 0.f;
    float s = ex;
    for (int o = 32; o > 0; o >>= 1) s += __shfl_xor(s, o);
    float res = v - m - logf(s);
    if (lane < 50) {
        if (flag[0]) ((bf16*)out)[row * 50 + f] = f2b(res);
        else         ((float*)out)[row * 50 + f] = res;
    }
}

extern "C" void kernel_launch(void* const* d_in, const int* in_sizes, int n_in,
                              void* d_out, int out_size, void* d_ws, size_t ws_size,
                              hipStream_t stream) {
    const void* x_raw = d_in[0];
    const int*  ei    = (const int*)d_in[1];
    const int*  et    = (const int*)d_in[2];
    const int*  tgt   = (const int*)d_in[3];

    char* wsp = (char*)d_ws;
    size_t off_b = 0;
    auto alloc = [&](size_t bytes) {
        void* p = wsp + off_b;
        off_b = (off_b + bytes + 255) & ~(size_t)255;
        return p;
    };
    unsigned char* Y8 = (unsigned char*)alloc((size_t)N_NODES * 256);       // 25.6 MB
    bf16*  R    = (bf16*) alloc((size_t)N_NODES * 64 * sizeof(bf16));       // 12.8 MB
    bf16*  xc   = (bf16*) alloc((size_t)N_NODES * 128 * sizeof(bf16));      // 25.6 MB
    bf16*  h    = xc;   // alias: xc dead after layer-1 GEMM
    unsigned int* se = (unsigned int*)alloc((size_t)N_EDGES * sizeof(unsigned int)); // 6.4 MB
    unsigned long long* staging = (unsigned long long*)alloc((size_t)NBUCK * BCAP * 8); // 21 MB
    int*   offs = (int*)  alloc((size_t)(N_NODES + 1) * sizeof(int));
    unsigned* bucketFill = (unsigned*)alloc((size_t)NBUCK * sizeof(unsigned));
    float* wc   = (float*)alloc((size_t)W_TOTAL * sizeof(float));
    bf16*  Wb1  = (bf16*) alloc((size_t)40960 * sizeof(bf16));
    bf16*  Wb2  = (bf16*) alloc((size_t)20480 * sizeof(bf16));
    float* rt1  = (float*)alloc((size_t)N_REL2 * 50 * sizeof(float));
    float* rt2  = (float*)alloc((size_t)N_REL2 * 50 * sizeof(float));
    float* c81  = (float*)alloc((size_t)N_REL2 * 8 * sizeof(float));
    float* c82  = (float*)alloc((size_t)N_REL2 * 8 * sizeof(float));
    int*   flag = (int*)  alloc(sizeof(int));

    const int* srcp = ei;
    const int* dstp = ei + N_EDGES;

    hipMemsetAsync(bucketFill, 0, (size_t)NBUCK * sizeof(unsigned), stream);

    WPtrs wp;
    for (int i = 0; i < 10; ++i) wp.p[i] = d_in[4 + i];

    k_detect<<<1, 256, 0, stream>>>((const unsigned short*)x_raw, flag);
    k_prep1<<<P1_TOTAL, 256, 0, stream>>>(x_raw, flag, xc, wp, wc, srcp, dstp, et,
                                          bucketFill, staging);
    k_prep2<<<P2_TOTAL, 256, 0, stream>>>(wc, Wb1, Wb2, rt1, rt2, c81, c82);
    k_bucket<<<NBUCK, 1024, 0, stream>>>(staging, bucketFill, offs, se);

    // Layer 1
    k_gemm_mfma<128, true><<<(N_NODES + 63) / 64, 256, 0, stream>>>(xc, Wb1, Y8, R, N_NODES, tgt);
    k_reduce1<<<(N_NODES + 3) / 4, 256, 0, stream>>>(offs, se, c81, rt1, Y8, R, wc + O_BIAS1, h);

    // Layer 2
    k_gemm_mfma<64, false><<<(N_NODES + 63) / 64, 256, 0, stream>>>(h, Wb2, Y8, R, N_NODES, nullptr);
    k_reduce2<<<(N_NODES + 3) / 4, 256, 0, stream>>>(offs, se, c82, rt2, Y8, R, wc + O_BIAS2, flag, d_out);
}